// Round 1
// 1276.496 us; speedup vs baseline: 1.1059x; 1.1059x over previous
//
#include <hip/hip_runtime.h>
#include <hip/hip_bf16.h>
#include <math.h>

#define NN 50000
#define NE 1600000
#define D 64
#define DE 32
#define H 4
#define DH 16
#define L 3

typedef __attribute__((ext_vector_type(8))) short bf16x8;
typedef __attribute__((ext_vector_type(8))) short s16x8;
typedef __attribute__((ext_vector_type(4))) float f32x4;

__device__ __forceinline__ short f2b(float f) {
    __hip_bfloat16 h = __float2bfloat16(f);
    short s;
    __builtin_memcpy(&s, &h, 2);
    return s;
}
__device__ __forceinline__ float b2f(unsigned short u) {
    unsigned int x = ((unsigned int)u) << 16;
    float f; __builtin_memcpy(&f, &x, 4); return f;
}
__device__ __forceinline__ float b2f_lo(unsigned int p) {
    unsigned int x = p << 16;
    float f; __builtin_memcpy(&f, &x, 4); return f;
}
__device__ __forceinline__ float b2f_hi(unsigned int p) {
    unsigned int x = p & 0xffff0000u;
    float f; __builtin_memcpy(&f, &x, 4); return f;
}

// ======================= CSR build (per launch) =======================

__global__ void deg_kernel(const int* __restrict__ dst, int* __restrict__ cnt) {
    int e = blockIdx.x * 256 + threadIdx.x;
    if (e >= NE) return;
    atomicAdd(&cnt[dst[e]], 1);
}

__global__ void block_sum_kernel(const int* __restrict__ cnt, int* __restrict__ bsum) {
    int b = blockIdx.x, t = threadIdx.x;
    int base = b * 1024 + t * 4;
    int s = 0;
#pragma unroll
    for (int i = 0; i < 4; i++) { int idx = base + i; if (idx < NN) s += cnt[idx]; }
#pragma unroll
    for (int off = 32; off; off >>= 1) s += __shfl_down(s, off);
    __shared__ int wsum[4];
    if ((t & 63) == 0) wsum[t >> 6] = s;
    __syncthreads();
    if (t == 0) bsum[b] = wsum[0] + wsum[1] + wsum[2] + wsum[3];
}

__global__ void scan_bsum_kernel(int* __restrict__ bsum, int nb) {
    if (blockIdx.x == 0 && threadIdx.x == 0) {
        int run = 0;
        for (int i = 0; i < nb; i++) { int c = bsum[i]; bsum[i] = run; run += c; }
    }
}

__global__ void scan_block_kernel(const int* __restrict__ cnt, const int* __restrict__ bsum,
                                  int* __restrict__ offsets) {
    int b = blockIdx.x, t = threadIdx.x;
    int base = b * 1024 + t * 4;
    int v[4]; int s = 0;
#pragma unroll
    for (int i = 0; i < 4; i++) { int idx = base + i; v[i] = (idx < NN) ? cnt[idx] : 0; s += v[i]; }
    int lane = t & 63, w = t >> 6;
    int x = s;
#pragma unroll
    for (int off = 1; off < 64; off <<= 1) {
        int y = __shfl_up(x, off);
        if (lane >= off) x += y;
    }
    __shared__ int wsum[4];
    if (lane == 63) wsum[w] = x;
    __syncthreads();
    int woff = 0;
    for (int i = 0; i < w; i++) woff += wsum[i];
    int run = bsum[b] + woff + x - s;
#pragma unroll
    for (int i = 0; i < 4; i++) {
        int idx = base + i;
        if (idx < NN) offsets[idx] = run;
        run += v[i];
    }
}

__global__ void scatter_kernel(const int* __restrict__ src, const int* __restrict__ dst,
                               const int* __restrict__ offsets,
                               int* __restrict__ cursor,
                               int* __restrict__ sorted_eid,
                               int* __restrict__ sorted_src,
                               int* __restrict__ sorted_dst) {
    int e = blockIdx.x * 256 + threadIdx.x;
    if (e >= NE) return;
    int d0 = dst[e];
    int pos = atomicAdd(&cursor[d0], 1);
    int position = offsets[d0] + pos;
    sorted_eid[position] = e;
    sorted_src[position] = src[e];
    sorted_dst[position] = d0;
}

// ---- permute pristine fp32 e into dst-sorted bf16 eb_s, fused layer-0
// edge bias (from the pristine fp32 values — exact w.r.t. reference) ----
__global__ void eperm_kernel(const float* __restrict__ e32, const int* __restrict__ sorted_eid,
                             const float* __restrict__ We0,
                             unsigned short* __restrict__ eb_s,
                             float* __restrict__ ebias_s) {
    int t = blockIdx.x * 256 + threadIdx.x;
    if (t >= NE * 4) return;
    int p = t >> 2;
    int c = (t & 3) * 8;
    int eid = sorted_eid[p];
    const float* ep = e32 + (size_t)eid * DE + c;
    float4 x0 = *(const float4*)(ep);
    float4 x1 = *(const float4*)(ep + 4);
    float e8[8] = {x0.x, x0.y, x0.z, x0.w, x1.x, x1.y, x1.z, x1.w};
    s16x8 ob;
#pragma unroll
    for (int i = 0; i < 8; i++) ob[i] = f2b(e8[i]);
    *(s16x8*)(eb_s + (size_t)p * DE + c) = ob;
    // fused layer-0 bias: partial dot over this thread's 8 cols, reduce over
    // the 4 threads (consecutive lanes) of this edge
    float p0 = 0.f, p1 = 0.f, p2 = 0.f, p3 = 0.f;
#pragma unroll
    for (int i = 0; i < 8; i++) {
        float4 w = *(const float4*)(We0 + (c + i) * 4);
        p0 += e8[i] * w.x; p1 += e8[i] * w.y; p2 += e8[i] * w.z; p3 += e8[i] * w.w;
    }
#pragma unroll
    for (int off = 1; off < 4; off <<= 1) {
        p0 += __shfl_xor(p0, off, 4);
        p1 += __shfl_xor(p1, off, 4);
        p2 += __shfl_xor(p2, off, 4);
        p3 += __shfl_xor(p3, off, 4);
    }
    if ((t & 3) == 0) {
        float4 o; o.x = p0; o.y = p1; o.z = p2; o.w = p3;
        *(float4*)(ebias_s + (size_t)p * H) = o;
    }
}

// ---- Wem[L][160][32] fp32 -> Wt[L][32][160] bf16 (transposed) ----
__global__ void wconv_kernel(const float* __restrict__ Wem, unsigned short* __restrict__ Wt) {
    int t = blockIdx.x * 256 + threadIdx.x;
    if (t >= L * 32 * 160) return;
    int l = t / 5120;
    int r = t % 5120;
    int n = r / 160;
    int k = r % 160;
    Wt[t] = (unsigned short)f2b(Wem[l * 5120 + k * 32 + n]);
}

// ---- h = node_features (fp32) + hb = bf16(node_features) ----
__global__ void hconv_kernel(const float* __restrict__ nf, float* __restrict__ h,
                             unsigned short* __restrict__ hb) {
    int t = blockIdx.x * 256 + threadIdx.x;
    if (t >= NN * D) return;
    float x = nf[t];
    h[t] = x;
    hb[t] = (unsigned short)f2b(x);
}

// ======================= per-layer kernels =======================

// ---- q = (h@Wq)*0.25 ; kv = pack(bf16(k), bf16(v)) ; 16 nodes/block ----
__global__ void qkv_kernel(const float* __restrict__ h,
                           const float* __restrict__ Wq,
                           const float* __restrict__ Wk,
                           const float* __restrict__ Wv,
                           float* __restrict__ q, unsigned int* __restrict__ kv) {
    __shared__ float sW[3 * 4096];   // 48 KB
    __shared__ float sh[16][D];
    int col = threadIdx.x;           // 0..63
    int wv = threadIdx.y;            // 0..3
    int tid = wv * 64 + col;
    int base = blockIdx.x * 16;
    for (int i = tid; i < 4096; i += 256) {
        sW[i] = Wq[i]; sW[4096 + i] = Wk[i]; sW[8192 + i] = Wv[i];
    }
    for (int i = tid; i < 16 * D; i += 256) {
        int n = base + (i >> 6);
        sh[i >> 6][i & 63] = h[n * D + (i & 63)];
    }
    __syncthreads();
#pragma unroll
    for (int it = 0; it < 4; it++) {
        int ln = wv * 4 + it;
        int node = base + ln;
        float aq = 0.f, ak = 0.f, av = 0.f;
#pragma unroll
        for (int kk = 0; kk < D; kk++) {
            float hv = sh[ln][kk];
            aq += hv * sW[kk * D + col];
            ak += hv * sW[4096 + kk * D + col];
            av += hv * sW[8192 + kk * D + col];
        }
        q[node * D + col] = aq * 0.25f;
        unsigned int kb = (unsigned int)(unsigned short)f2b(ak);
        unsigned int vb = (unsigned int)(unsigned short)f2b(av);
        kv[node * D + col] = (vb << 16) | kb;
    }
}

// ---- fused per-dst-node online-softmax attention + aggregation (8-wide) ----
__global__ void attn_kernel(const float* __restrict__ q, const unsigned int* __restrict__ kv,
                            const float* __restrict__ ebias_s,
                            const int* __restrict__ sorted_src,
                            const int* __restrict__ offsets,
                            float* __restrict__ agg) {
    int node = blockIdx.x * 4 + threadIdx.y;
    node = __builtin_amdgcn_readfirstlane(node);
    if (node >= NN) return;
    int lane = threadIdx.x;
    int hh = lane >> 4;
    float qv = q[node * D + lane];
    int beg = offsets[node];
    int end = (node == NN - 1) ? NE : offsets[node + 1];
    float mmax = -INFINITY, den = 0.f, acc = 0.f;
    int i = beg;
    for (; i + 8 <= end; i += 8) {
        int ss[8]; unsigned int kk8[8]; float bb8[8], dd[8];
#pragma unroll
        for (int u = 0; u < 8; u++) ss[u] = sorted_src[i + u];
#pragma unroll
        for (int u = 0; u < 8; u++) kk8[u] = kv[ss[u] * D + lane];
#pragma unroll
        for (int u = 0; u < 8; u++) bb8[u] = ebias_s[(i + u) * H + hh];
#pragma unroll
        for (int u = 0; u < 8; u++) dd[u] = qv * b2f_lo(kk8[u]);
#pragma unroll
        for (int off = 1; off < 16; off <<= 1) {
#pragma unroll
            for (int u = 0; u < 8; u++) dd[u] += __shfl_xor(dd[u], off, 16);
        }
        float nm = mmax;
#pragma unroll
        for (int u = 0; u < 8; u++) { dd[u] += bb8[u]; nm = fmaxf(nm, dd[u]); }
        float scale = __expf(mmax - nm);
        float ps = 0.f, av = 0.f;
#pragma unroll
        for (int u = 0; u < 8; u++) {
            float p = __expf(dd[u] - nm);
            ps += p;
            av += p * b2f_hi(kk8[u]);
        }
        den = den * scale + ps;
        acc = acc * scale + av;
        mmax = nm;
    }
    for (; i < end; i++) {
        int s = sorted_src[i];
        unsigned int kvv = kv[s * D + lane];
        float b = ebias_s[i * H + hh];
        float dot = qv * b2f_lo(kvv);
#pragma unroll
        for (int off = 1; off < 16; off <<= 1) dot += __shfl_xor(dot, off, 16);
        float score = dot + b;
        float nm = fmaxf(mmax, score);
        float scale = __expf(mmax - nm);
        float p = __expf(score - nm);
        den = den * scale + p;
        acc = acc * scale + p * b2f_hi(kvv);
        mmax = nm;
    }
    agg[node * D + lane] = acc / (den + 1e-9f);
}

// ---- h = LN(h + agg @ Wo) + bf16 shadow ; 16 nodes/block ----
__global__ void node_update_kernel(float* __restrict__ h, const float* __restrict__ agg,
                                   const float* __restrict__ Wo,
                                   const float* __restrict__ gn,
                                   const float* __restrict__ bn,
                                   unsigned short* __restrict__ hb) {
    __shared__ float sWo[4096];      // 16 KB
    __shared__ float sagg[16][D];
    int col = threadIdx.x, wv = threadIdx.y;
    int tid = wv * 64 + col;
    int base = blockIdx.x * 16;
    for (int i = tid; i < 4096; i += 256) sWo[i] = Wo[i];
    for (int i = tid; i < 16 * D; i += 256) {
        int n = base + (i >> 6);
        sagg[i >> 6][i & 63] = agg[n * D + (i & 63)];
    }
    __syncthreads();
    float gcol = gn[col], bcol = bn[col];
#pragma unroll
    for (int it = 0; it < 4; it++) {
        int ln = wv * 4 + it;
        int node = base + ln;
        float acc = 0.f;
#pragma unroll
        for (int kk = 0; kk < D; kk++) acc += sagg[ln][kk] * sWo[kk * D + col];
        float x = h[node * D + col] + acc;
        float sum = x, sq = x * x;
#pragma unroll
        for (int off = 32; off; off >>= 1) {
            sum += __shfl_xor(sum, off);
            sq += __shfl_xor(sq, off);
        }
        float mu = sum * (1.f / 64.f);
        float var = sq * (1.f / 64.f) - mu * mu;
        float out = (x - mu) * rsqrtf(var + 1e-5f) * gcol + bcol;
        h[node * D + col] = out;
        hb[node * D + col] = (unsigned short)f2b(out);
    }
}

// ---- e = LN(e + gelu([h[src]|h[dst]|e] @ Wem + bem)) via bf16 MFMA.
// All edge state in dst-sorted position order: eb_s read/write contiguous,
// next-layer ebias_s written contiguous (no rank scatter).
// do_estore=0 skips the eb_s write-back (last kept layer: only the fused
// next-layer bias output is live).
__global__ void edge_update_mfma_kernel(const unsigned short* __restrict__ hb,
                                        unsigned short* __restrict__ eb_s,
                                        const int* __restrict__ sorted_src,
                                        const int* __restrict__ sorted_dst,
                                        const unsigned short* __restrict__ Wt,   // [32][160] bf16
                                        const float* __restrict__ bem,
                                        const float* __restrict__ ge,
                                        const float* __restrict__ be,
                                        const float* __restrict__ We_next,       // [32][4]
                                        float* __restrict__ ebias_s,
                                        int do_bias, int do_estore) {
    int wave = threadIdx.x >> 6;
    int lane = threadIdx.x & 63;
    int we = blockIdx.x * 64 + wave * 16;       // first sorted position of this wave
    int m = lane & 15;
    int quad = lane >> 4;
    int p_m = we + m;
    int s_idx = sorted_src[p_m], d_idx = sorted_dst[p_m];

    const unsigned short* as = hb + (size_t)s_idx * D + quad * 8;
    const unsigned short* ad = hb + (size_t)d_idx * D + quad * 8;
    const unsigned short* w0 = Wt + m * 160 + quad * 8;

    f32x4 c0 = {0.f, 0.f, 0.f, 0.f};
    f32x4 c1 = {0.f, 0.f, 0.f, 0.f};

#pragma unroll
    for (int ks = 0; ks < 4; ks++) {
        const unsigned short* ap = (ks < 2) ? as : ad;
        bf16x8 a = *(const bf16x8*)(ap + (ks & 1) * 32);
        bf16x8 b0 = *(const bf16x8*)(w0 + ks * 32);
        bf16x8 b1 = *(const bf16x8*)(w0 + ks * 32 + 16 * 160);
        c0 = __builtin_amdgcn_mfma_f32_16x16x32_bf16(a, b0, c0, 0, 0, 0);
        c1 = __builtin_amdgcn_mfma_f32_16x16x32_bf16(a, b1, c1, 0, 0, 0);
    }
    {
        bf16x8 a = *(const bf16x8*)(eb_s + (size_t)p_m * DE + quad * 8);
        bf16x8 b0 = *(const bf16x8*)(w0 + 4 * 32);
        bf16x8 b1 = *(const bf16x8*)(w0 + 4 * 32 + 16 * 160);
        c0 = __builtin_amdgcn_mfma_f32_16x16x32_bf16(a, b0, c0, 0, 0, 0);
        c1 = __builtin_amdgcn_mfma_f32_16x16x32_bf16(a, b1, c1, 0, 0, 0);
    }

    // epilogue: C/D layout col=lane&15, row=quad*4+reg
    float bm0 = bem[m], bm1 = bem[m + 16];
    float g0 = ge[m], g1 = ge[m + 16];
    float bb0 = be[m], bb1 = be[m + 16];
    float4 wn0 = {0, 0, 0, 0}, wn1 = {0, 0, 0, 0};
    if (do_bias) {
        wn0 = *(const float4*)(We_next + m * 4);
        wn1 = *(const float4*)(We_next + (m + 16) * 4);
    }
#pragma unroll
    for (int reg = 0; reg < 4; reg++) {
        int er = we + quad * 4 + reg;            // sorted position of this C-row
        float y0 = c0[reg] + bm0;
        float y1 = c1[reg] + bm1;
        float u0 = 1.5957691216057308f * (y0 + 0.044715f * y0 * y0 * y0);
        float u1 = 1.5957691216057308f * (y1 + 0.044715f * y1 * y1 * y1);
        float t0 = 1.f - 2.f / (1.f + __expf(u0));
        float t1 = 1.f - 2.f / (1.f + __expf(u1));
        y0 = 0.5f * y0 * (1.f + t0);
        y1 = 0.5f * y1 * (1.f + t1);
        float eo0 = b2f(eb_s[(size_t)er * DE + m]);
        float eo1 = b2f(eb_s[(size_t)er * DE + m + 16]);
        y0 += eo0;
        y1 += eo1;
        float s = y0 + y1, sq = y0 * y0 + y1 * y1;
#pragma unroll
        for (int off = 1; off < 16; off <<= 1) {
            s += __shfl_xor(s, off, 16);
            sq += __shfl_xor(sq, off, 16);
        }
        float mu = s * (1.f / 32.f);
        float var = sq * (1.f / 32.f) - mu * mu;
        float inv = rsqrtf(var + 1e-5f);
        float z0 = (y0 - mu) * inv * g0 + bb0;
        float z1 = (y1 - mu) * inv * g1 + bb1;
        if (do_estore) {
            eb_s[(size_t)er * DE + m] = (unsigned short)f2b(z0);
            eb_s[(size_t)er * DE + m + 16] = (unsigned short)f2b(z1);
        }
        if (do_bias) {
            float p0 = z0 * wn0.x + z1 * wn1.x;
            float p1 = z0 * wn0.y + z1 * wn1.y;
            float p2 = z0 * wn0.z + z1 * wn1.z;
            float p3 = z0 * wn0.w + z1 * wn1.w;
#pragma unroll
            for (int off = 1; off < 16; off <<= 1) {
                p0 += __shfl_xor(p0, off, 16);
                p1 += __shfl_xor(p1, off, 16);
                p2 += __shfl_xor(p2, off, 16);
                p3 += __shfl_xor(p3, off, 16);
            }
            if (m < 4) {
                float bsel = (m == 0) ? p0 : (m == 1) ? p1 : (m == 2) ? p2 : p3;
                ebias_s[er * H + m] = bsel;   // contiguous by position
            }
        }
    }
}

extern "C" void kernel_launch(void* const* d_in, const int* in_sizes, int n_in,
                              void* d_out, int out_size, void* d_ws, size_t ws_size,
                              hipStream_t stream) {
    const float* node_features = (const float*)d_in[0];
    const float* e = (const float*)d_in[1];   // pristine fp32 e (read-only)
    const int* edge_index = (const int*)d_in[2];
    const int* src = edge_index;
    const int* dst = edge_index + NE;
    const float* Wq = (const float*)d_in[3];
    const float* Wk = (const float*)d_in[4];
    const float* Wv = (const float*)d_in[5];
    const float* Wo = (const float*)d_in[6];
    const float* We = (const float*)d_in[7];
    const float* Wem = (const float*)d_in[8];
    const float* bem = (const float*)d_in[9];
    const float* gn = (const float*)d_in[10];
    const float* bn = (const float*)d_in[11];
    const float* ge = (const float*)d_in[12];
    const float* be = (const float*)d_in[13];

    float* h = (float*)d_out;       // h lives in d_out

    float* ws = (float*)d_ws;
    float* q = ws;                                       // N*D f32
    unsigned int* kv = (unsigned int*)(q + NN * D);      // N*D u32 (packed bf16 k|v)
    float* agg = (float*)(kv + NN * D);                  // N*D f32
    float* ebias_s = agg + NN * D;                       // E*H f32 (sorted order)
    int* offsets = (int*)(ebias_s + (size_t)NE * H);     // NN
    int* cursor = offsets + NN;                          // NN
    int* bsum = cursor + NN;                             // 64
    int* sorted_eid = bsum + 64;                         // NE
    int* sorted_src = sorted_eid + NE;                   // NE
    int* sorted_dst = sorted_src + NE;                   // NE
    unsigned short* Wt = (unsigned short*)(sorted_dst + NE);  // L*32*160 bf16
    unsigned short* hb = Wt + L * 32 * 160;              // N*D bf16
    unsigned short* eb_s = hb + NN * D;                  // E*DE bf16 e-state (sorted)

    const int NB = (NN + 1023) / 1024;

    // ---- CSR build + preconverts (inputs constant; rebuilt every launch) ----
    hipMemsetAsync(cursor, 0, NN * sizeof(int), stream);
    deg_kernel<<<(NE + 255) / 256, 256, 0, stream>>>(dst, cursor);
    block_sum_kernel<<<NB, 256, 0, stream>>>(cursor, bsum);
    scan_bsum_kernel<<<1, 64, 0, stream>>>(bsum, NB);
    scan_block_kernel<<<NB, 256, 0, stream>>>(cursor, bsum, offsets);
    hipMemsetAsync(cursor, 0, NN * sizeof(int), stream);
    scatter_kernel<<<(NE + 255) / 256, 256, 0, stream>>>(src, dst, offsets, cursor,
                                                         sorted_eid, sorted_src, sorted_dst);
    // eperm also produces the layer-0 edge bias (fused, from pristine fp32 e)
    eperm_kernel<<<(NE * 4 + 255) / 256, 256, 0, stream>>>(e, sorted_eid, We, eb_s, ebias_s);
    wconv_kernel<<<(L * 32 * 160 + 255) / 256, 256, 0, stream>>>(Wem, Wt);
    hconv_kernel<<<(NN * D + 255) / 256, 256, 0, stream>>>(node_features, h, hb);

    for (int layer = 0; layer < L; layer++) {
        const float* Wq_l = Wq + layer * D * D;
        const float* Wk_l = Wk + layer * D * D;
        const float* Wv_l = Wv + layer * D * D;
        const float* Wo_l = Wo + layer * D * D;
        const unsigned short* Wt_l = Wt + layer * 32 * 160;
        const float* bem_l = bem + layer * DE;
        const float* gn_l = gn + layer * D;
        const float* bn_l = bn + layer * D;
        const float* ge_l = ge + layer * DE;
        const float* be_l = be + layer * DE;

        qkv_kernel<<<NN / 16, dim3(64, 4), 0, stream>>>(h, Wq_l, Wk_l, Wv_l, q, kv);
        attn_kernel<<<NN / 4, dim3(64, 4), 0, stream>>>(q, kv, ebias_s, sorted_src,
                                                        offsets, agg);
        node_update_kernel<<<NN / 16, dim3(64, 4), 0, stream>>>(h, agg, Wo_l,
                                                                gn_l, bn_l, hb);
        // The final h does not depend on the last layer's edge update (the
        // reference returns h only), so:
        //   layer 0: full edge update (eb_s + next-layer bias)
        //   layer 1: bias-only (eb_s state is dead afterwards)
        //   layer 2: skipped entirely
        if (layer < L - 1) {
            const float* We_next = We + (layer + 1) * DE * H;
            edge_update_mfma_kernel<<<NE / 64, 256, 0, stream>>>(hb, eb_s, sorted_src,
                                                                 sorted_dst, Wt_l,
                                                                 bem_l, ge_l, be_l,
                                                                 We_next, ebias_s,
                                                                 1, layer == 0 ? 1 : 0);
        }
    }
}

// Round 2
// 1276.437 us; speedup vs baseline: 1.1060x; 1.0000x over previous
//
#include <hip/hip_runtime.h>
#include <hip/hip_bf16.h>
#include <math.h>

#define NN 50000
#define NE 1600000
#define D 64
#define DE 32
#define H 4
#define DH 16
#define L 3

typedef __attribute__((ext_vector_type(8))) short bf16x8;
typedef __attribute__((ext_vector_type(8))) short s16x8;
typedef __attribute__((ext_vector_type(4))) float f32x4;

__device__ __forceinline__ short f2b(float f) {
    __hip_bfloat16 h = __float2bfloat16(f);
    short s;
    __builtin_memcpy(&s, &h, 2);
    return s;
}
__device__ __forceinline__ float b2f(unsigned short u) {
    unsigned int x = ((unsigned int)u) << 16;
    float f; __builtin_memcpy(&f, &x, 4); return f;
}
__device__ __forceinline__ float b2f_lo(unsigned int p) {
    unsigned int x = p << 16;
    float f; __builtin_memcpy(&f, &x, 4); return f;
}
__device__ __forceinline__ float b2f_hi(unsigned int p) {
    unsigned int x = p & 0xffff0000u;
    float f; __builtin_memcpy(&f, &x, 4); return f;
}

// ======================= CSR build (per launch) =======================

__global__ void deg_kernel(const int* __restrict__ dst, int* __restrict__ cnt) {
    int e = blockIdx.x * 256 + threadIdx.x;
    if (e >= NE) return;
    atomicAdd(&cnt[dst[e]], 1);
}

__global__ void block_sum_kernel(const int* __restrict__ cnt, int* __restrict__ bsum) {
    int b = blockIdx.x, t = threadIdx.x;
    int base = b * 1024 + t * 4;
    int s = 0;
#pragma unroll
    for (int i = 0; i < 4; i++) { int idx = base + i; if (idx < NN) s += cnt[idx]; }
#pragma unroll
    for (int off = 32; off; off >>= 1) s += __shfl_down(s, off);
    __shared__ int wsum[4];
    if ((t & 63) == 0) wsum[t >> 6] = s;
    __syncthreads();
    if (t == 0) bsum[b] = wsum[0] + wsum[1] + wsum[2] + wsum[3];
}

__global__ void scan_bsum_kernel(int* __restrict__ bsum, int nb) {
    if (blockIdx.x == 0 && threadIdx.x == 0) {
        int run = 0;
        for (int i = 0; i < nb; i++) { int c = bsum[i]; bsum[i] = run; run += c; }
    }
}

__global__ void scan_block_kernel(const int* __restrict__ cnt, const int* __restrict__ bsum,
                                  int* __restrict__ offsets) {
    int b = blockIdx.x, t = threadIdx.x;
    int base = b * 1024 + t * 4;
    int v[4]; int s = 0;
#pragma unroll
    for (int i = 0; i < 4; i++) { int idx = base + i; v[i] = (idx < NN) ? cnt[idx] : 0; s += v[i]; }
    int lane = t & 63, w = t >> 6;
    int x = s;
#pragma unroll
    for (int off = 1; off < 64; off <<= 1) {
        int y = __shfl_up(x, off);
        if (lane >= off) x += y;
    }
    __shared__ int wsum[4];
    if (lane == 63) wsum[w] = x;
    __syncthreads();
    int woff = 0;
    for (int i = 0; i < w; i++) woff += wsum[i];
    int run = bsum[b] + woff + x - s;
#pragma unroll
    for (int i = 0; i < 4; i++) {
        int idx = base + i;
        if (idx < NN) offsets[idx] = run;
        run += v[i];
    }
}

__global__ void scatter_kernel(const int* __restrict__ src, const int* __restrict__ dst,
                               const int* __restrict__ offsets,
                               int* __restrict__ cursor,
                               int* __restrict__ sorted_eid,
                               int* __restrict__ sorted_src,
                               int* __restrict__ sorted_dst) {
    int e = blockIdx.x * 256 + threadIdx.x;
    if (e >= NE) return;
    int d0 = dst[e];
    int pos = atomicAdd(&cursor[d0], 1);
    int position = offsets[d0] + pos;
    sorted_eid[position] = e;
    sorted_src[position] = src[e];
    sorted_dst[position] = d0;
}

// ---- permute pristine fp32 e into dst-sorted bf16 eb_s, fused layer-0
// edge bias (from the pristine fp32 values — exact w.r.t. reference) ----
__global__ void eperm_kernel(const float* __restrict__ e32, const int* __restrict__ sorted_eid,
                             const float* __restrict__ We0,
                             unsigned short* __restrict__ eb_s,
                             float* __restrict__ ebias_s) {
    int t = blockIdx.x * 256 + threadIdx.x;
    if (t >= NE * 4) return;
    int p = t >> 2;
    int c = (t & 3) * 8;
    int eid = sorted_eid[p];
    const float* ep = e32 + (size_t)eid * DE + c;
    float4 x0 = *(const float4*)(ep);
    float4 x1 = *(const float4*)(ep + 4);
    float e8[8] = {x0.x, x0.y, x0.z, x0.w, x1.x, x1.y, x1.z, x1.w};
    s16x8 ob;
#pragma unroll
    for (int i = 0; i < 8; i++) ob[i] = f2b(e8[i]);
    *(s16x8*)(eb_s + (size_t)p * DE + c) = ob;
    // fused layer-0 bias: partial dot over this thread's 8 cols, reduce over
    // the 4 threads (consecutive lanes) of this edge
    float p0 = 0.f, p1 = 0.f, p2 = 0.f, p3 = 0.f;
#pragma unroll
    for (int i = 0; i < 8; i++) {
        float4 w = *(const float4*)(We0 + (c + i) * 4);
        p0 += e8[i] * w.x; p1 += e8[i] * w.y; p2 += e8[i] * w.z; p3 += e8[i] * w.w;
    }
#pragma unroll
    for (int off = 1; off < 4; off <<= 1) {
        p0 += __shfl_xor(p0, off, 4);
        p1 += __shfl_xor(p1, off, 4);
        p2 += __shfl_xor(p2, off, 4);
        p3 += __shfl_xor(p3, off, 4);
    }
    if ((t & 3) == 0) {
        float4 o; o.x = p0; o.y = p1; o.z = p2; o.w = p3;
        *(float4*)(ebias_s + (size_t)p * H) = o;
    }
}

// ---- Wem[L][160][32] fp32 -> Wt[L][32][160] bf16 (transposed) ----
__global__ void wconv_kernel(const float* __restrict__ Wem, unsigned short* __restrict__ Wt) {
    int t = blockIdx.x * 256 + threadIdx.x;
    if (t >= L * 32 * 160) return;
    int l = t / 5120;
    int r = t % 5120;
    int n = r / 160;
    int k = r % 160;
    Wt[t] = (unsigned short)f2b(Wem[l * 5120 + k * 32 + n]);
}

// ---- h = node_features (fp32) + hb = bf16(node_features) ----
__global__ void hconv_kernel(const float* __restrict__ nf, float* __restrict__ h,
                             unsigned short* __restrict__ hb) {
    int t = blockIdx.x * 256 + threadIdx.x;
    if (t >= NN * D) return;
    float x = nf[t];
    h[t] = x;
    hb[t] = (unsigned short)f2b(x);
}

// ======================= per-layer kernels =======================

// ---- q = (h@Wq)*0.25 ; kv = pack(bf16(k), bf16(v)) ; 16 nodes/block ----
__global__ void qkv_kernel(const float* __restrict__ h,
                           const float* __restrict__ Wq,
                           const float* __restrict__ Wk,
                           const float* __restrict__ Wv,
                           float* __restrict__ q, unsigned int* __restrict__ kv) {
    __shared__ float sW[3 * 4096];   // 48 KB
    __shared__ float sh[16][D];
    int col = threadIdx.x;           // 0..63
    int wv = threadIdx.y;            // 0..3
    int tid = wv * 64 + col;
    int base = blockIdx.x * 16;
    for (int i = tid; i < 4096; i += 256) {
        sW[i] = Wq[i]; sW[4096 + i] = Wk[i]; sW[8192 + i] = Wv[i];
    }
    for (int i = tid; i < 16 * D; i += 256) {
        int n = base + (i >> 6);
        sh[i >> 6][i & 63] = h[n * D + (i & 63)];
    }
    __syncthreads();
#pragma unroll
    for (int it = 0; it < 4; it++) {
        int ln = wv * 4 + it;
        int node = base + ln;
        float aq = 0.f, ak = 0.f, av = 0.f;
#pragma unroll
        for (int kk = 0; kk < D; kk++) {
            float hv = sh[ln][kk];
            aq += hv * sW[kk * D + col];
            ak += hv * sW[4096 + kk * D + col];
            av += hv * sW[8192 + kk * D + col];
        }
        q[node * D + col] = aq * 0.25f;
        unsigned int kb = (unsigned int)(unsigned short)f2b(ak);
        unsigned int vb = (unsigned int)(unsigned short)f2b(av);
        kv[node * D + col] = (vb << 16) | kb;
    }
}

// ---- fused per-dst-node online-softmax attention + aggregation (8-wide) ----
__global__ void attn_kernel(const float* __restrict__ q, const unsigned int* __restrict__ kv,
                            const float* __restrict__ ebias_s,
                            const int* __restrict__ sorted_src,
                            const int* __restrict__ offsets,
                            float* __restrict__ agg) {
    int node = blockIdx.x * 4 + threadIdx.y;
    node = __builtin_amdgcn_readfirstlane(node);
    if (node >= NN) return;
    int lane = threadIdx.x;
    int hh = lane >> 4;
    float qv = q[node * D + lane];
    int beg = offsets[node];
    int end = (node == NN - 1) ? NE : offsets[node + 1];
    float mmax = -INFINITY, den = 0.f, acc = 0.f;
    int i = beg;
    for (; i + 8 <= end; i += 8) {
        int ss[8]; unsigned int kk8[8]; float bb8[8], dd[8];
#pragma unroll
        for (int u = 0; u < 8; u++) ss[u] = sorted_src[i + u];
#pragma unroll
        for (int u = 0; u < 8; u++) kk8[u] = kv[ss[u] * D + lane];
#pragma unroll
        for (int u = 0; u < 8; u++) bb8[u] = ebias_s[(i + u) * H + hh];
#pragma unroll
        for (int u = 0; u < 8; u++) dd[u] = qv * b2f_lo(kk8[u]);
#pragma unroll
        for (int off = 1; off < 16; off <<= 1) {
#pragma unroll
            for (int u = 0; u < 8; u++) dd[u] += __shfl_xor(dd[u], off, 16);
        }
        float nm = mmax;
#pragma unroll
        for (int u = 0; u < 8; u++) { dd[u] += bb8[u]; nm = fmaxf(nm, dd[u]); }
        float scale = __expf(mmax - nm);
        float ps = 0.f, av = 0.f;
#pragma unroll
        for (int u = 0; u < 8; u++) {
            float p = __expf(dd[u] - nm);
            ps += p;
            av += p * b2f_hi(kk8[u]);
        }
        den = den * scale + ps;
        acc = acc * scale + av;
        mmax = nm;
    }
    for (; i < end; i++) {
        int s = sorted_src[i];
        unsigned int kvv = kv[s * D + lane];
        float b = ebias_s[i * H + hh];
        float dot = qv * b2f_lo(kvv);
#pragma unroll
        for (int off = 1; off < 16; off <<= 1) dot += __shfl_xor(dot, off, 16);
        float score = dot + b;
        float nm = fmaxf(mmax, score);
        float scale = __expf(mmax - nm);
        float p = __expf(score - nm);
        den = den * scale + p;
        acc = acc * scale + p * b2f_hi(kvv);
        mmax = nm;
    }
    agg[node * D + lane] = acc / (den + 1e-9f);
}

// ---- h = LN(h + agg @ Wo) + bf16 shadow ; 16 nodes/block ----
__global__ void node_update_kernel(float* __restrict__ h, const float* __restrict__ agg,
                                   const float* __restrict__ Wo,
                                   const float* __restrict__ gn,
                                   const float* __restrict__ bn,
                                   unsigned short* __restrict__ hb) {
    __shared__ float sWo[4096];      // 16 KB
    __shared__ float sagg[16][D];
    int col = threadIdx.x, wv = threadIdx.y;
    int tid = wv * 64 + col;
    int base = blockIdx.x * 16;
    for (int i = tid; i < 4096; i += 256) sWo[i] = Wo[i];
    for (int i = tid; i < 16 * D; i += 256) {
        int n = base + (i >> 6);
        sagg[i >> 6][i & 63] = agg[n * D + (i & 63)];
    }
    __syncthreads();
    float gcol = gn[col], bcol = bn[col];
#pragma unroll
    for (int it = 0; it < 4; it++) {
        int ln = wv * 4 + it;
        int node = base + ln;
        float acc = 0.f;
#pragma unroll
        for (int kk = 0; kk < D; kk++) acc += sagg[ln][kk] * sWo[kk * D + col];
        float x = h[node * D + col] + acc;
        float sum = x, sq = x * x;
#pragma unroll
        for (int off = 32; off; off >>= 1) {
            sum += __shfl_xor(sum, off);
            sq += __shfl_xor(sq, off);
        }
        float mu = sum * (1.f / 64.f);
        float var = sq * (1.f / 64.f) - mu * mu;
        float out = (x - mu) * rsqrtf(var + 1e-5f) * gcol + bcol;
        h[node * D + col] = out;
        hb[node * D + col] = (unsigned short)f2b(out);
    }
}

// ---- e = LN(e + gelu([h[src]|h[dst]|e] @ Wem + bem)) via bf16 MFMA.
// Epilogue transposed through LDS so each lane owns one full edge row:
//   - residual comes free from the kept eb_s A-fragment (same row/col slice)
//   - LN reduce: 4 shuffles (over quads) instead of 32
//   - next-layer bias: one extra MFMA (z is directly an A-fragment) instead
//     of 64 shuffles
//   - eb_s store: one dwordx4 instead of 8 scalar ushort stores
__global__ void edge_update_mfma_kernel(const unsigned short* __restrict__ hb,
                                        unsigned short* __restrict__ eb_s,
                                        const int* __restrict__ sorted_src,
                                        const int* __restrict__ sorted_dst,
                                        const unsigned short* __restrict__ Wt,   // [32][160] bf16
                                        const float* __restrict__ bem,
                                        const float* __restrict__ ge,
                                        const float* __restrict__ be,
                                        const float* __restrict__ We_next,       // [32][4]
                                        float* __restrict__ ebias_s,
                                        int do_bias, int do_estore) {
    __shared__ __align__(16) float ytr[4][16][36];   // pad 36: 16B-aligned rows, 2-way banks
    int wave = threadIdx.x >> 6;
    int lane = threadIdx.x & 63;
    int we = blockIdx.x * 64 + wave * 16;       // first sorted position of this wave
    int m = lane & 15;
    int quad = lane >> 4;
    int p_m = we + m;
    int s_idx = sorted_src[p_m], d_idx = sorted_dst[p_m];

    const unsigned short* as = hb + (size_t)s_idx * D + quad * 8;
    const unsigned short* ad = hb + (size_t)d_idx * D + quad * 8;
    const unsigned short* w0 = Wt + m * 160 + quad * 8;

    // B-fragment of We_next (bias MFMA), built once: lane holds
    // B[k=quad*8+j][n=m] = We_next[(quad*8+j)*4 + m] for m<4, else 0.
    bf16x8 wb;
#pragma unroll
    for (int j = 0; j < 8; j++) {
        float w = (do_bias && m < 4) ? We_next[(quad * 8 + j) * 4 + m] : 0.f;
        wb[j] = f2b(w);
    }

    f32x4 c0 = {0.f, 0.f, 0.f, 0.f};
    f32x4 c1 = {0.f, 0.f, 0.f, 0.f};

#pragma unroll
    for (int ks = 0; ks < 4; ks++) {
        const unsigned short* ap = (ks < 2) ? as : ad;
        bf16x8 a = *(const bf16x8*)(ap + (ks & 1) * 32);
        bf16x8 b0 = *(const bf16x8*)(w0 + ks * 32);
        bf16x8 b1 = *(const bf16x8*)(w0 + ks * 32 + 16 * 160);
        c0 = __builtin_amdgcn_mfma_f32_16x16x32_bf16(a, b0, c0, 0, 0, 0);
        c1 = __builtin_amdgcn_mfma_f32_16x16x32_bf16(a, b1, c1, 0, 0, 0);
    }
    // e-state A-fragment: row we+m, cols quad*8..+8 — ALSO the residual this
    // lane needs after the transpose (row-owned layout), so keep it.
    bf16x8 ea = *(const bf16x8*)(eb_s + (size_t)p_m * DE + quad * 8);
    {
        bf16x8 b0 = *(const bf16x8*)(w0 + 4 * 32);
        bf16x8 b1 = *(const bf16x8*)(w0 + 4 * 32 + 16 * 160);
        c0 = __builtin_amdgcn_mfma_f32_16x16x32_bf16(ea, b0, c0, 0, 0, 0);
        c1 = __builtin_amdgcn_mfma_f32_16x16x32_bf16(ea, b1, c1, 0, 0, 0);
    }

    // gelu(mfma + bem) in C-layout (col=m / m+16, row=quad*4+reg) -> LDS
    float bm0 = bem[m], bm1 = bem[m + 16];
#pragma unroll
    for (int reg = 0; reg < 4; reg++) {
        int row = quad * 4 + reg;
        float y0 = c0[reg] + bm0;
        float y1 = c1[reg] + bm1;
        float u0 = 1.5957691216057308f * (y0 + 0.044715f * y0 * y0 * y0);
        float u1 = 1.5957691216057308f * (y1 + 0.044715f * y1 * y1 * y1);
        float t0 = 1.f - 2.f / (1.f + __expf(u0));
        float t1 = 1.f - 2.f / (1.f + __expf(u1));
        ytr[wave][row][m] = 0.5f * y0 * (1.f + t0);
        ytr[wave][row][m + 16] = 0.5f * y1 * (1.f + t1);
    }
    __syncthreads();

    // row-owned: lane handles edge (we+m), cols quad*8..+8
    float y[8];
    *(f32x4*)&y[0] = *(const f32x4*)&ytr[wave][m][quad * 8];
    *(f32x4*)&y[4] = *(const f32x4*)&ytr[wave][m][quad * 8 + 4];
    float s = 0.f, sq = 0.f;
#pragma unroll
    for (int j = 0; j < 8; j++) {
        y[j] += b2f((unsigned short)ea[j]);      // residual (free, from A-frag)
        s += y[j];
        sq += y[j] * y[j];
    }
    s += __shfl_xor(s, 16); s += __shfl_xor(s, 32);
    sq += __shfl_xor(sq, 16); sq += __shfl_xor(sq, 32);
    float mu = s * (1.f / 32.f);
    float var = sq * (1.f / 32.f) - mu * mu;
    float inv = rsqrtf(var + 1e-5f);

    float4 g0 = *(const float4*)(ge + quad * 8);
    float4 g1 = *(const float4*)(ge + quad * 8 + 4);
    float4 b0 = *(const float4*)(be + quad * 8);
    float4 b1 = *(const float4*)(be + quad * 8 + 4);
    float gg[8] = {g0.x, g0.y, g0.z, g0.w, g1.x, g1.y, g1.z, g1.w};
    float bbv[8] = {b0.x, b0.y, b0.z, b0.w, b1.x, b1.y, b1.z, b1.w};
    bf16x8 zb;
#pragma unroll
    for (int j = 0; j < 8; j++) {
        float z = (y[j] - mu) * inv * gg[j] + bbv[j];
        zb[j] = f2b(z);
    }
    if (do_estore) {
        *(s16x8*)(eb_s + (size_t)p_m * DE + quad * 8) = zb;
    }
    if (do_bias) {
        // bias[edge][head] = z · We_next : z is directly an A-fragment
        f32x4 db = {0.f, 0.f, 0.f, 0.f};
        db = __builtin_amdgcn_mfma_f32_16x16x32_bf16(zb, wb, db, 0, 0, 0);
        // D layout: col=lane&15 = head, row=quad*4+reg = edge-in-group
        if (m < 4) {
#pragma unroll
            for (int reg = 0; reg < 4; reg++) {
                ebias_s[(we + quad * 4 + reg) * H + m] = db[reg];
            }
        }
    }
}

extern "C" void kernel_launch(void* const* d_in, const int* in_sizes, int n_in,
                              void* d_out, int out_size, void* d_ws, size_t ws_size,
                              hipStream_t stream) {
    const float* node_features = (const float*)d_in[0];
    const float* e = (const float*)d_in[1];   // pristine fp32 e (read-only)
    const int* edge_index = (const int*)d_in[2];
    const int* src = edge_index;
    const int* dst = edge_index + NE;
    const float* Wq = (const float*)d_in[3];
    const float* Wk = (const float*)d_in[4];
    const float* Wv = (const float*)d_in[5];
    const float* Wo = (const float*)d_in[6];
    const float* We = (const float*)d_in[7];
    const float* Wem = (const float*)d_in[8];
    const float* bem = (const float*)d_in[9];
    const float* gn = (const float*)d_in[10];
    const float* bn = (const float*)d_in[11];
    const float* ge = (const float*)d_in[12];
    const float* be = (const float*)d_in[13];

    float* h = (float*)d_out;       // h lives in d_out

    float* ws = (float*)d_ws;
    float* q = ws;                                       // N*D f32
    unsigned int* kv = (unsigned int*)(q + NN * D);      // N*D u32 (packed bf16 k|v)
    float* agg = (float*)(kv + NN * D);                  // N*D f32
    float* ebias_s = agg + NN * D;                       // E*H f32 (sorted order)
    int* offsets = (int*)(ebias_s + (size_t)NE * H);     // NN
    int* cursor = offsets + NN;                          // NN
    int* bsum = cursor + NN;                             // 64
    int* sorted_eid = bsum + 64;                         // NE
    int* sorted_src = sorted_eid + NE;                   // NE
    int* sorted_dst = sorted_src + NE;                   // NE
    unsigned short* Wt = (unsigned short*)(sorted_dst + NE);  // L*32*160 bf16
    unsigned short* hb = Wt + L * 32 * 160;              // N*D bf16
    unsigned short* eb_s = hb + NN * D;                  // E*DE bf16 e-state (sorted)

    const int NB = (NN + 1023) / 1024;

    // ---- CSR build + preconverts (inputs constant; rebuilt every launch) ----
    hipMemsetAsync(cursor, 0, NN * sizeof(int), stream);
    deg_kernel<<<(NE + 255) / 256, 256, 0, stream>>>(dst, cursor);
    block_sum_kernel<<<NB, 256, 0, stream>>>(cursor, bsum);
    scan_bsum_kernel<<<1, 64, 0, stream>>>(bsum, NB);
    scan_block_kernel<<<NB, 256, 0, stream>>>(cursor, bsum, offsets);
    hipMemsetAsync(cursor, 0, NN * sizeof(int), stream);
    scatter_kernel<<<(NE + 255) / 256, 256, 0, stream>>>(src, dst, offsets, cursor,
                                                         sorted_eid, sorted_src, sorted_dst);
    // eperm also produces the layer-0 edge bias (fused, from pristine fp32 e)
    eperm_kernel<<<(NE * 4 + 255) / 256, 256, 0, stream>>>(e, sorted_eid, We, eb_s, ebias_s);
    wconv_kernel<<<(L * 32 * 160 + 255) / 256, 256, 0, stream>>>(Wem, Wt);
    hconv_kernel<<<(NN * D + 255) / 256, 256, 0, stream>>>(node_features, h, hb);

    for (int layer = 0; layer < L; layer++) {
        const float* Wq_l = Wq + layer * D * D;
        const float* Wk_l = Wk + layer * D * D;
        const float* Wv_l = Wv + layer * D * D;
        const float* Wo_l = Wo + layer * D * D;
        const unsigned short* Wt_l = Wt + layer * 32 * 160;
        const float* bem_l = bem + layer * DE;
        const float* gn_l = gn + layer * D;
        const float* bn_l = bn + layer * D;
        const float* ge_l = ge + layer * DE;
        const float* be_l = be + layer * DE;

        qkv_kernel<<<NN / 16, dim3(64, 4), 0, stream>>>(h, Wq_l, Wk_l, Wv_l, q, kv);
        attn_kernel<<<NN / 4, dim3(64, 4), 0, stream>>>(q, kv, ebias_s, sorted_src,
                                                        offsets, agg);
        node_update_kernel<<<NN / 16, dim3(64, 4), 0, stream>>>(h, agg, Wo_l,
                                                                gn_l, bn_l, hb);
        // The final h does not depend on the last layer's edge update (the
        // reference returns h only), so:
        //   layer 0: full edge update (eb_s + next-layer bias)
        //   layer 1: bias-only (eb_s state is dead afterwards)
        //   layer 2: skipped entirely
        if (layer < L - 1) {
            const float* We_next = We + (layer + 1) * DE * H;
            edge_update_mfma_kernel<<<NE / 64, 256, 0, stream>>>(hb, eb_s, sorted_src,
                                                                 sorted_dst, Wt_l,
                                                                 bem_l, ge_l, be_l,
                                                                 We_next, ebias_s,
                                                                 1, layer == 0 ? 1 : 0);
        }
    }
}

// Round 3
// 1230.130 us; speedup vs baseline: 1.1476x; 1.0376x over previous
//
#include <hip/hip_runtime.h>
#include <hip/hip_bf16.h>
#include <math.h>

#define NN 50000
#define NE 1600000
#define D 64
#define DE 32
#define H 4
#define DH 16
#define L 3

typedef __attribute__((ext_vector_type(8))) short bf16x8;
typedef __attribute__((ext_vector_type(8))) short s16x8;
typedef __attribute__((ext_vector_type(4))) float f32x4;

__device__ __forceinline__ short f2b(float f) {
    __hip_bfloat16 h = __float2bfloat16(f);
    short s;
    __builtin_memcpy(&s, &h, 2);
    return s;
}
__device__ __forceinline__ float b2f(unsigned short u) {
    unsigned int x = ((unsigned int)u) << 16;
    float f; __builtin_memcpy(&f, &x, 4); return f;
}
__device__ __forceinline__ float b2f_lo(unsigned int p) {
    unsigned int x = p << 16;
    float f; __builtin_memcpy(&f, &x, 4); return f;
}
__device__ __forceinline__ float b2f_hi(unsigned int p) {
    unsigned int x = p & 0xffff0000u;
    float f; __builtin_memcpy(&f, &x, 4); return f;
}

// ======================= CSR build (per launch) =======================

__global__ void deg_kernel(const int* __restrict__ dst, int* __restrict__ cnt) {
    int e = blockIdx.x * 256 + threadIdx.x;
    if (e >= NE) return;
    atomicAdd(&cnt[dst[e]], 1);
}

__global__ void block_sum_kernel(const int* __restrict__ cnt, int* __restrict__ bsum) {
    int b = blockIdx.x, t = threadIdx.x;
    int base = b * 1024 + t * 4;
    int s = 0;
#pragma unroll
    for (int i = 0; i < 4; i++) { int idx = base + i; if (idx < NN) s += cnt[idx]; }
#pragma unroll
    for (int off = 32; off; off >>= 1) s += __shfl_down(s, off);
    __shared__ int wsum[4];
    if ((t & 63) == 0) wsum[t >> 6] = s;
    __syncthreads();
    if (t == 0) bsum[b] = wsum[0] + wsum[1] + wsum[2] + wsum[3];
}

__global__ void scan_bsum_kernel(int* __restrict__ bsum, int nb) {
    if (blockIdx.x == 0 && threadIdx.x == 0) {
        int run = 0;
        for (int i = 0; i < nb; i++) { int c = bsum[i]; bsum[i] = run; run += c; }
    }
}

__global__ void scan_block_kernel(const int* __restrict__ cnt, const int* __restrict__ bsum,
                                  int* __restrict__ offsets) {
    int b = blockIdx.x, t = threadIdx.x;
    int base = b * 1024 + t * 4;
    int v[4]; int s = 0;
#pragma unroll
    for (int i = 0; i < 4; i++) { int idx = base + i; v[i] = (idx < NN) ? cnt[idx] : 0; s += v[i]; }
    int lane = t & 63, w = t >> 6;
    int x = s;
#pragma unroll
    for (int off = 1; off < 64; off <<= 1) {
        int y = __shfl_up(x, off);
        if (lane >= off) x += y;
    }
    __shared__ int wsum[4];
    if (lane == 63) wsum[w] = x;
    __syncthreads();
    int woff = 0;
    for (int i = 0; i < w; i++) woff += wsum[i];
    int run = bsum[b] + woff + x - s;
#pragma unroll
    for (int i = 0; i < 4; i++) {
        int idx = base + i;
        if (idx < NN) offsets[idx] = run;
        run += v[i];
    }
}

__global__ void scatter_kernel(const int* __restrict__ src, const int* __restrict__ dst,
                               const int* __restrict__ offsets,
                               int* __restrict__ cursor,
                               int* __restrict__ sorted_eid,
                               int* __restrict__ sorted_src,
                               int* __restrict__ sorted_dst) {
    int e = blockIdx.x * 256 + threadIdx.x;
    if (e >= NE) return;
    int d0 = dst[e];
    int pos = atomicAdd(&cursor[d0], 1);
    int position = offsets[d0] + pos;
    sorted_eid[position] = e;
    sorted_src[position] = src[e];
    sorted_dst[position] = d0;
}

// ---- permute pristine fp32 e into dst-sorted bf16 eb_s, fused layer-0
// edge bias (from the pristine fp32 values — exact w.r.t. reference) ----
__global__ void eperm_kernel(const float* __restrict__ e32, const int* __restrict__ sorted_eid,
                             const float* __restrict__ We0,
                             unsigned short* __restrict__ eb_s,
                             float* __restrict__ ebias_s) {
    int t = blockIdx.x * 256 + threadIdx.x;
    if (t >= NE * 4) return;
    int p = t >> 2;
    int c = (t & 3) * 8;
    int eid = sorted_eid[p];
    const float* ep = e32 + (size_t)eid * DE + c;
    float4 x0 = *(const float4*)(ep);
    float4 x1 = *(const float4*)(ep + 4);
    float e8[8] = {x0.x, x0.y, x0.z, x0.w, x1.x, x1.y, x1.z, x1.w};
    s16x8 ob;
#pragma unroll
    for (int i = 0; i < 8; i++) ob[i] = f2b(e8[i]);
    *(s16x8*)(eb_s + (size_t)p * DE + c) = ob;
    // fused layer-0 bias: partial dot over this thread's 8 cols, reduce over
    // the 4 threads (consecutive lanes) of this edge
    float p0 = 0.f, p1 = 0.f, p2 = 0.f, p3 = 0.f;
#pragma unroll
    for (int i = 0; i < 8; i++) {
        float4 w = *(const float4*)(We0 + (c + i) * 4);
        p0 += e8[i] * w.x; p1 += e8[i] * w.y; p2 += e8[i] * w.z; p3 += e8[i] * w.w;
    }
#pragma unroll
    for (int off = 1; off < 4; off <<= 1) {
        p0 += __shfl_xor(p0, off, 4);
        p1 += __shfl_xor(p1, off, 4);
        p2 += __shfl_xor(p2, off, 4);
        p3 += __shfl_xor(p3, off, 4);
    }
    if ((t & 3) == 0) {
        float4 o; o.x = p0; o.y = p1; o.z = p2; o.w = p3;
        *(float4*)(ebias_s + (size_t)p * H) = o;
    }
}

// ---- Wem[L][160][32] fp32 -> Wt[L][32][160] bf16 (transposed) ----
__global__ void wconv_kernel(const float* __restrict__ Wem, unsigned short* __restrict__ Wt) {
    int t = blockIdx.x * 256 + threadIdx.x;
    if (t >= L * 32 * 160) return;
    int l = t / 5120;
    int r = t % 5120;
    int n = r / 160;
    int k = r % 160;
    Wt[t] = (unsigned short)f2b(Wem[l * 5120 + k * 32 + n]);
}

// ---- h = node_features (fp32) + hb = bf16(node_features) ----
__global__ void hconv_kernel(const float* __restrict__ nf, float* __restrict__ h,
                             unsigned short* __restrict__ hb) {
    int t = blockIdx.x * 256 + threadIdx.x;
    if (t >= NN * D) return;
    float x = nf[t];
    h[t] = x;
    hb[t] = (unsigned short)f2b(x);
}

// ======================= per-layer kernels =======================

// ---- q = (h@Wq)*0.25 ; kv = pack(bf16(k), bf16(v)) ; 16 nodes/block ----
__global__ void qkv_kernel(const float* __restrict__ h,
                           const float* __restrict__ Wq,
                           const float* __restrict__ Wk,
                           const float* __restrict__ Wv,
                           float* __restrict__ q, unsigned int* __restrict__ kv) {
    __shared__ float sW[3 * 4096];   // 48 KB
    __shared__ float sh[16][D];
    int col = threadIdx.x;           // 0..63
    int wv = threadIdx.y;            // 0..3
    int tid = wv * 64 + col;
    int base = blockIdx.x * 16;
    for (int i = tid; i < 4096; i += 256) {
        sW[i] = Wq[i]; sW[4096 + i] = Wk[i]; sW[8192 + i] = Wv[i];
    }
    for (int i = tid; i < 16 * D; i += 256) {
        int n = base + (i >> 6);
        sh[i >> 6][i & 63] = h[n * D + (i & 63)];
    }
    __syncthreads();
#pragma unroll
    for (int it = 0; it < 4; it++) {
        int ln = wv * 4 + it;
        int node = base + ln;
        float aq = 0.f, ak = 0.f, av = 0.f;
#pragma unroll
        for (int kk = 0; kk < D; kk++) {
            float hv = sh[ln][kk];
            aq += hv * sW[kk * D + col];
            ak += hv * sW[4096 + kk * D + col];
            av += hv * sW[8192 + kk * D + col];
        }
        q[node * D + col] = aq * 0.25f;
        unsigned int kb = (unsigned int)(unsigned short)f2b(ak);
        unsigned int vb = (unsigned int)(unsigned short)f2b(av);
        kv[node * D + col] = (vb << 16) | kb;
    }
}

// ---- fused per-dst-node online-softmax attention + aggregation (8-wide) ----
__global__ void attn_kernel(const float* __restrict__ q, const unsigned int* __restrict__ kv,
                            const float* __restrict__ ebias_s,
                            const int* __restrict__ sorted_src,
                            const int* __restrict__ offsets,
                            float* __restrict__ agg) {
    int node = blockIdx.x * 4 + threadIdx.y;
    node = __builtin_amdgcn_readfirstlane(node);
    if (node >= NN) return;
    int lane = threadIdx.x;
    int hh = lane >> 4;
    float qv = q[node * D + lane];
    int beg = offsets[node];
    int end = (node == NN - 1) ? NE : offsets[node + 1];
    float mmax = -INFINITY, den = 0.f, acc = 0.f;
    int i = beg;
    for (; i + 8 <= end; i += 8) {
        int ss[8]; unsigned int kk8[8]; float bb8[8], dd[8];
#pragma unroll
        for (int u = 0; u < 8; u++) ss[u] = sorted_src[i + u];
#pragma unroll
        for (int u = 0; u < 8; u++) kk8[u] = kv[ss[u] * D + lane];
#pragma unroll
        for (int u = 0; u < 8; u++) bb8[u] = ebias_s[(i + u) * H + hh];
#pragma unroll
        for (int u = 0; u < 8; u++) dd[u] = qv * b2f_lo(kk8[u]);
#pragma unroll
        for (int off = 1; off < 16; off <<= 1) {
#pragma unroll
            for (int u = 0; u < 8; u++) dd[u] += __shfl_xor(dd[u], off, 16);
        }
        float nm = mmax;
#pragma unroll
        for (int u = 0; u < 8; u++) { dd[u] += bb8[u]; nm = fmaxf(nm, dd[u]); }
        float scale = __expf(mmax - nm);
        float ps = 0.f, av = 0.f;
#pragma unroll
        for (int u = 0; u < 8; u++) {
            float p = __expf(dd[u] - nm);
            ps += p;
            av += p * b2f_hi(kk8[u]);
        }
        den = den * scale + ps;
        acc = acc * scale + av;
        mmax = nm;
    }
    for (; i < end; i++) {
        int s = sorted_src[i];
        unsigned int kvv = kv[s * D + lane];
        float b = ebias_s[i * H + hh];
        float dot = qv * b2f_lo(kvv);
#pragma unroll
        for (int off = 1; off < 16; off <<= 1) dot += __shfl_xor(dot, off, 16);
        float score = dot + b;
        float nm = fmaxf(mmax, score);
        float scale = __expf(mmax - nm);
        float p = __expf(score - nm);
        den = den * scale + p;
        acc = acc * scale + p * b2f_hi(kvv);
        mmax = nm;
    }
    agg[node * D + lane] = acc / (den + 1e-9f);
}

// ---- h = LN(h + agg @ Wo) + bf16 shadow ; 16 nodes/block ----
__global__ void node_update_kernel(float* __restrict__ h, const float* __restrict__ agg,
                                   const float* __restrict__ Wo,
                                   const float* __restrict__ gn,
                                   const float* __restrict__ bn,
                                   unsigned short* __restrict__ hb) {
    __shared__ float sWo[4096];      // 16 KB
    __shared__ float sagg[16][D];
    int col = threadIdx.x, wv = threadIdx.y;
    int tid = wv * 64 + col;
    int base = blockIdx.x * 16;
    for (int i = tid; i < 4096; i += 256) sWo[i] = Wo[i];
    for (int i = tid; i < 16 * D; i += 256) {
        int n = base + (i >> 6);
        sagg[i >> 6][i & 63] = agg[n * D + (i & 63)];
    }
    __syncthreads();
    float gcol = gn[col], bcol = bn[col];
#pragma unroll
    for (int it = 0; it < 4; it++) {
        int ln = wv * 4 + it;
        int node = base + ln;
        float acc = 0.f;
#pragma unroll
        for (int kk = 0; kk < D; kk++) acc += sagg[ln][kk] * sWo[kk * D + col];
        float x = h[node * D + col] + acc;
        float sum = x, sq = x * x;
#pragma unroll
        for (int off = 32; off; off >>= 1) {
            sum += __shfl_xor(sum, off);
            sq += __shfl_xor(sq, off);
        }
        float mu = sum * (1.f / 64.f);
        float var = sq * (1.f / 64.f) - mu * mu;
        float out = (x - mu) * rsqrtf(var + 1e-5f) * gcol + bcol;
        h[node * D + col] = out;
        hb[node * D + col] = (unsigned short)f2b(out);
    }
}

// ---- e = LN(e + gelu([h[src]|h[dst]|e] @ Wem + bem)) via bf16 MFMA.
// v3: fight register-starvation serialization (VGPR_Count was 32 →
// weights re-fetched from global before every MFMA, serial vmcnt chain):
//   - __launch_bounds__(256,4): allow 128 VGPRs
//   - Wt staged in LDS (padded 168-short rows → ≥2-way banks only);
//     B-frags via ds_read_b128, no global serialization
//   - all 5 gather frags issued before the staging barrier (latency hides
//     under weight staging)
// Epilogue (LDS transpose, row-owned LN, bias via extra MFMA) unchanged.
__global__ __launch_bounds__(256, 4)
void edge_update_mfma_kernel(const unsigned short* __restrict__ hb,
                             unsigned short* __restrict__ eb_s,
                             const int* __restrict__ sorted_src,
                             const int* __restrict__ sorted_dst,
                             const unsigned short* __restrict__ Wt,   // [32][160] bf16
                             const float* __restrict__ bem,
                             const float* __restrict__ ge,
                             const float* __restrict__ be,
                             const float* __restrict__ We_next,       // [32][4]
                             float* __restrict__ ebias_s,
                             int do_bias, int do_estore) {
    __shared__ __align__(16) unsigned short sWt[32][168];  // 160 + 8 pad
    __shared__ __align__(16) float ytr[4][16][36];
    int tid = threadIdx.x;
    int wave = tid >> 6;
    int lane = tid & 63;
    int we = blockIdx.x * 64 + wave * 16;       // first sorted position of this wave
    int m = lane & 15;
    int quad = lane >> 4;
    int p_m = we + m;
    int s_idx = sorted_src[p_m], d_idx = sorted_dst[p_m];

    // issue all gathers up-front (latency overlaps the weight staging below)
    const unsigned short* as = hb + (size_t)s_idx * D + quad * 8;
    const unsigned short* ad = hb + (size_t)d_idx * D + quad * 8;
    bf16x8 a_s0 = *(const bf16x8*)(as);
    bf16x8 a_s1 = *(const bf16x8*)(as + 32);
    bf16x8 a_d0 = *(const bf16x8*)(ad);
    bf16x8 a_d1 = *(const bf16x8*)(ad + 32);
    bf16x8 ea = *(const bf16x8*)(eb_s + (size_t)p_m * DE + quad * 8);

    // stage Wt[32][160] -> sWt[32][168] (2560 dwords, 10 per thread)
    {
        const unsigned int* Wt32 = (const unsigned int*)Wt;
#pragma unroll
        for (int it = 0; it < 10; it++) {
            int i = tid + it * 256;
            int sh = i * 2;
            int r = sh / 160, c = sh % 160;
            *(unsigned int*)&sWt[r][c] = Wt32[i];
        }
    }

    // B-fragment of We_next (bias MFMA): lane holds
    // B[k=quad*8+j][n=m] = We_next[(quad*8+j)*4 + m] for m<4, else 0.
    bf16x8 wb;
#pragma unroll
    for (int j = 0; j < 8; j++) {
        float w = (do_bias && m < 4) ? We_next[(quad * 8 + j) * 4 + m] : 0.f;
        wb[j] = f2b(w);
    }

    __syncthreads();    // weights staged

    f32x4 c0 = {0.f, 0.f, 0.f, 0.f};
    f32x4 c1 = {0.f, 0.f, 0.f, 0.f};
    const unsigned short* w0 = &sWt[m][quad * 8];
    const unsigned short* w1 = &sWt[m + 16][quad * 8];

#pragma unroll
    for (int ks = 0; ks < 4; ks++) {
        bf16x8 a = (ks == 0) ? a_s0 : (ks == 1) ? a_s1 : (ks == 2) ? a_d0 : a_d1;
        bf16x8 b0 = *(const bf16x8*)(w0 + ks * 32);
        bf16x8 b1 = *(const bf16x8*)(w1 + ks * 32);
        c0 = __builtin_amdgcn_mfma_f32_16x16x32_bf16(a, b0, c0, 0, 0, 0);
        c1 = __builtin_amdgcn_mfma_f32_16x16x32_bf16(a, b1, c1, 0, 0, 0);
    }
    {
        bf16x8 b0 = *(const bf16x8*)(w0 + 4 * 32);
        bf16x8 b1 = *(const bf16x8*)(w1 + 4 * 32);
        c0 = __builtin_amdgcn_mfma_f32_16x16x32_bf16(ea, b0, c0, 0, 0, 0);
        c1 = __builtin_amdgcn_mfma_f32_16x16x32_bf16(ea, b1, c1, 0, 0, 0);
    }

    // gelu(mfma + bem) in C-layout (col=m / m+16, row=quad*4+reg) -> LDS
    float bm0 = bem[m], bm1 = bem[m + 16];
#pragma unroll
    for (int reg = 0; reg < 4; reg++) {
        int row = quad * 4 + reg;
        float y0 = c0[reg] + bm0;
        float y1 = c1[reg] + bm1;
        float u0 = 1.5957691216057308f * (y0 + 0.044715f * y0 * y0 * y0);
        float u1 = 1.5957691216057308f * (y1 + 0.044715f * y1 * y1 * y1);
        float t0 = 1.f - 2.f / (1.f + __expf(u0));
        float t1 = 1.f - 2.f / (1.f + __expf(u1));
        ytr[wave][row][m] = 0.5f * y0 * (1.f + t0);
        ytr[wave][row][m + 16] = 0.5f * y1 * (1.f + t1);
    }
    __syncthreads();

    // row-owned: lane handles edge (we+m), cols quad*8..+8
    float y[8];
    *(f32x4*)&y[0] = *(const f32x4*)&ytr[wave][m][quad * 8];
    *(f32x4*)&y[4] = *(const f32x4*)&ytr[wave][m][quad * 8 + 4];
    float s = 0.f, sq = 0.f;
#pragma unroll
    for (int j = 0; j < 8; j++) {
        y[j] += b2f((unsigned short)ea[j]);      // residual (free, from A-frag)
        s += y[j];
        sq += y[j] * y[j];
    }
    s += __shfl_xor(s, 16); s += __shfl_xor(s, 32);
    sq += __shfl_xor(sq, 16); sq += __shfl_xor(sq, 32);
    float mu = s * (1.f / 32.f);
    float var = sq * (1.f / 32.f) - mu * mu;
    float inv = rsqrtf(var + 1e-5f);

    float4 g0 = *(const float4*)(ge + quad * 8);
    float4 g1 = *(const float4*)(ge + quad * 8 + 4);
    float4 b0 = *(const float4*)(be + quad * 8);
    float4 b1 = *(const float4*)(be + quad * 8 + 4);
    float gg[8] = {g0.x, g0.y, g0.z, g0.w, g1.x, g1.y, g1.z, g1.w};
    float bbv[8] = {b0.x, b0.y, b0.z, b0.w, b1.x, b1.y, b1.z, b1.w};
    bf16x8 zb;
#pragma unroll
    for (int j = 0; j < 8; j++) {
        float z = (y[j] - mu) * inv * gg[j] + bbv[j];
        zb[j] = f2b(z);
    }
    if (do_estore) {
        *(s16x8*)(eb_s + (size_t)p_m * DE + quad * 8) = zb;
    }
    if (do_bias) {
        // bias[edge][head] = z · We_next : z is directly an A-fragment
        f32x4 db = {0.f, 0.f, 0.f, 0.f};
        db = __builtin_amdgcn_mfma_f32_16x16x32_bf16(zb, wb, db, 0, 0, 0);
        // D layout: col=lane&15 = head, row=quad*4+reg = edge-in-group
        if (m < 4) {
#pragma unroll
            for (int reg = 0; reg < 4; reg++) {
                ebias_s[(we + quad * 4 + reg) * H + m] = db[reg];
            }
        }
    }
}

extern "C" void kernel_launch(void* const* d_in, const int* in_sizes, int n_in,
                              void* d_out, int out_size, void* d_ws, size_t ws_size,
                              hipStream_t stream) {
    const float* node_features = (const float*)d_in[0];
    const float* e = (const float*)d_in[1];   // pristine fp32 e (read-only)
    const int* edge_index = (const int*)d_in[2];
    const int* src = edge_index;
    const int* dst = edge_index + NE;
    const float* Wq = (const float*)d_in[3];
    const float* Wk = (const float*)d_in[4];
    const float* Wv = (const float*)d_in[5];
    const float* Wo = (const float*)d_in[6];
    const float* We = (const float*)d_in[7];
    const float* Wem = (const float*)d_in[8];
    const float* bem = (const float*)d_in[9];
    const float* gn = (const float*)d_in[10];
    const float* bn = (const float*)d_in[11];
    const float* ge = (const float*)d_in[12];
    const float* be = (const float*)d_in[13];

    float* h = (float*)d_out;       // h lives in d_out

    float* ws = (float*)d_ws;
    float* q = ws;                                       // N*D f32
    unsigned int* kv = (unsigned int*)(q + NN * D);      // N*D u32 (packed bf16 k|v)
    float* agg = (float*)(kv + NN * D);                  // N*D f32
    float* ebias_s = agg + NN * D;                       // E*H f32 (sorted order)
    int* offsets = (int*)(ebias_s + (size_t)NE * H);     // NN
    int* cursor = offsets + NN;                          // NN
    int* bsum = cursor + NN;                             // 64
    int* sorted_eid = bsum + 64;                         // NE
    int* sorted_src = sorted_eid + NE;                   // NE
    int* sorted_dst = sorted_src + NE;                   // NE
    unsigned short* Wt = (unsigned short*)(sorted_dst + NE);  // L*32*160 bf16
    unsigned short* hb = Wt + L * 32 * 160;              // N*D bf16
    unsigned short* eb_s = hb + NN * D;                  // E*DE bf16 e-state (sorted)

    const int NB = (NN + 1023) / 1024;

    // ---- CSR build + preconverts (inputs constant; rebuilt every launch) ----
    hipMemsetAsync(cursor, 0, NN * sizeof(int), stream);
    deg_kernel<<<(NE + 255) / 256, 256, 0, stream>>>(dst, cursor);
    block_sum_kernel<<<NB, 256, 0, stream>>>(cursor, bsum);
    scan_bsum_kernel<<<1, 64, 0, stream>>>(bsum, NB);
    scan_block_kernel<<<NB, 256, 0, stream>>>(cursor, bsum, offsets);
    hipMemsetAsync(cursor, 0, NN * sizeof(int), stream);
    scatter_kernel<<<(NE + 255) / 256, 256, 0, stream>>>(src, dst, offsets, cursor,
                                                         sorted_eid, sorted_src, sorted_dst);
    // eperm also produces the layer-0 edge bias (fused, from pristine fp32 e)
    eperm_kernel<<<(NE * 4 + 255) / 256, 256, 0, stream>>>(e, sorted_eid, We, eb_s, ebias_s);
    wconv_kernel<<<(L * 32 * 160 + 255) / 256, 256, 0, stream>>>(Wem, Wt);
    hconv_kernel<<<(NN * D + 255) / 256, 256, 0, stream>>>(node_features, h, hb);

    for (int layer = 0; layer < L; layer++) {
        const float* Wq_l = Wq + layer * D * D;
        const float* Wk_l = Wk + layer * D * D;
        const float* Wv_l = Wv + layer * D * D;
        const float* Wo_l = Wo + layer * D * D;
        const unsigned short* Wt_l = Wt + layer * 32 * 160;
        const float* bem_l = bem + layer * DE;
        const float* gn_l = gn + layer * D;
        const float* bn_l = bn + layer * D;
        const float* ge_l = ge + layer * DE;
        const float* be_l = be + layer * DE;

        qkv_kernel<<<NN / 16, dim3(64, 4), 0, stream>>>(h, Wq_l, Wk_l, Wv_l, q, kv);
        attn_kernel<<<NN / 4, dim3(64, 4), 0, stream>>>(q, kv, ebias_s, sorted_src,
                                                        offsets, agg);
        node_update_kernel<<<NN / 16, dim3(64, 4), 0, stream>>>(h, agg, Wo_l,
                                                                gn_l, bn_l, hb);
        // The final h does not depend on the last layer's edge update (the
        // reference returns h only), so:
        //   layer 0: full edge update (eb_s + next-layer bias)
        //   layer 1: bias-only (eb_s state is dead afterwards)
        //   layer 2: skipped entirely
        if (layer < L - 1) {
            const float* We_next = We + (layer + 1) * DE * H;
            edge_update_mfma_kernel<<<NE / 64, 256, 0, stream>>>(hb, eb_s, sorted_src,
                                                                 sorted_dst, Wt_l,
                                                                 bem_l, ge_l, be_l,
                                                                 We_next, ebias_s,
                                                                 1, layer == 0 ? 1 : 0);
        }
    }
}

// Round 4
// 1132.046 us; speedup vs baseline: 1.2470x; 1.0866x over previous
//
#include <hip/hip_runtime.h>
#include <hip/hip_bf16.h>
#include <math.h>

#define NN 50000
#define NE 1600000
#define D 64
#define DE 32
#define H 4
#define DH 16
#define L 3

typedef __attribute__((ext_vector_type(8))) short bf16x8;
typedef __attribute__((ext_vector_type(8))) short s16x8;
typedef __attribute__((ext_vector_type(4))) float f32x4;

__device__ __forceinline__ short f2b(float f) {
    __hip_bfloat16 h = __float2bfloat16(f);
    short s;
    __builtin_memcpy(&s, &h, 2);
    return s;
}
__device__ __forceinline__ float b2f(unsigned short u) {
    unsigned int x = ((unsigned int)u) << 16;
    float f; __builtin_memcpy(&f, &x, 4); return f;
}
__device__ __forceinline__ float b2f_lo(unsigned int p) {
    unsigned int x = p << 16;
    float f; __builtin_memcpy(&f, &x, 4); return f;
}
__device__ __forceinline__ float b2f_hi(unsigned int p) {
    unsigned int x = p & 0xffff0000u;
    float f; __builtin_memcpy(&f, &x, 4); return f;
}

// ======================= CSR build (per launch) =======================

__global__ void deg_kernel(const int* __restrict__ dst, int* __restrict__ cnt) {
    int e = blockIdx.x * 256 + threadIdx.x;
    if (e >= NE) return;
    atomicAdd(&cnt[dst[e]], 1);
}

__global__ void block_sum_kernel(const int* __restrict__ cnt, int* __restrict__ bsum) {
    int b = blockIdx.x, t = threadIdx.x;
    int base = b * 1024 + t * 4;
    int s = 0;
#pragma unroll
    for (int i = 0; i < 4; i++) { int idx = base + i; if (idx < NN) s += cnt[idx]; }
#pragma unroll
    for (int off = 32; off; off >>= 1) s += __shfl_down(s, off);
    __shared__ int wsum[4];
    if ((t & 63) == 0) wsum[t >> 6] = s;
    __syncthreads();
    if (t == 0) bsum[b] = wsum[0] + wsum[1] + wsum[2] + wsum[3];
}

__global__ void scan_bsum_kernel(int* __restrict__ bsum, int nb) {
    if (blockIdx.x == 0 && threadIdx.x == 0) {
        int run = 0;
        for (int i = 0; i < nb; i++) { int c = bsum[i]; bsum[i] = run; run += c; }
    }
}

__global__ void scan_block_kernel(const int* __restrict__ cnt, const int* __restrict__ bsum,
                                  int* __restrict__ offsets) {
    int b = blockIdx.x, t = threadIdx.x;
    int base = b * 1024 + t * 4;
    int v[4]; int s = 0;
#pragma unroll
    for (int i = 0; i < 4; i++) { int idx = base + i; v[i] = (idx < NN) ? cnt[idx] : 0; s += v[i]; }
    int lane = t & 63, w = t >> 6;
    int x = s;
#pragma unroll
    for (int off = 1; off < 64; off <<= 1) {
        int y = __shfl_up(x, off);
        if (lane >= off) x += y;
    }
    __shared__ int wsum[4];
    if (lane == 63) wsum[w] = x;
    __syncthreads();
    int woff = 0;
    for (int i = 0; i < w; i++) woff += wsum[i];
    int run = bsum[b] + woff + x - s;
#pragma unroll
    for (int i = 0; i < 4; i++) {
        int idx = base + i;
        if (idx < NN) offsets[idx] = run;
        run += v[i];
    }
}

__global__ void scatter_kernel(const int* __restrict__ src, const int* __restrict__ dst,
                               const int* __restrict__ offsets,
                               int* __restrict__ cursor,
                               int* __restrict__ sorted_eid,
                               int* __restrict__ sorted_src,
                               int* __restrict__ sorted_dst) {
    int e = blockIdx.x * 256 + threadIdx.x;
    if (e >= NE) return;
    int d0 = dst[e];
    int pos = atomicAdd(&cursor[d0], 1);
    int position = offsets[d0] + pos;
    sorted_eid[position] = e;
    sorted_src[position] = src[e];
    sorted_dst[position] = d0;
}

// ---- permute pristine fp32 e into dst-sorted bf16 eb_s, fused layer-0
// edge bias (from the pristine fp32 values — exact w.r.t. reference) ----
__global__ void eperm_kernel(const float* __restrict__ e32, const int* __restrict__ sorted_eid,
                             const float* __restrict__ We0,
                             unsigned short* __restrict__ eb_s,
                             float* __restrict__ ebias_s) {
    int t = blockIdx.x * 256 + threadIdx.x;
    if (t >= NE * 4) return;
    int p = t >> 2;
    int c = (t & 3) * 8;
    int eid = sorted_eid[p];
    const float* ep = e32 + (size_t)eid * DE + c;
    float4 x0 = *(const float4*)(ep);
    float4 x1 = *(const float4*)(ep + 4);
    float e8[8] = {x0.x, x0.y, x0.z, x0.w, x1.x, x1.y, x1.z, x1.w};
    s16x8 ob;
#pragma unroll
    for (int i = 0; i < 8; i++) ob[i] = f2b(e8[i]);
    *(s16x8*)(eb_s + (size_t)p * DE + c) = ob;
    // fused layer-0 bias: partial dot over this thread's 8 cols, reduce over
    // the 4 threads (consecutive lanes) of this edge
    float p0 = 0.f, p1 = 0.f, p2 = 0.f, p3 = 0.f;
#pragma unroll
    for (int i = 0; i < 8; i++) {
        float4 w = *(const float4*)(We0 + (c + i) * 4);
        p0 += e8[i] * w.x; p1 += e8[i] * w.y; p2 += e8[i] * w.z; p3 += e8[i] * w.w;
    }
#pragma unroll
    for (int off = 1; off < 4; off <<= 1) {
        p0 += __shfl_xor(p0, off, 4);
        p1 += __shfl_xor(p1, off, 4);
        p2 += __shfl_xor(p2, off, 4);
        p3 += __shfl_xor(p3, off, 4);
    }
    if ((t & 3) == 0) {
        float4 o; o.x = p0; o.y = p1; o.z = p2; o.w = p3;
        *(float4*)(ebias_s + (size_t)p * H) = o;
    }
}

// ---- Wem[L][160][32] fp32 -> Wt[L][32][160] bf16 (transposed) ----
__global__ void wconv_kernel(const float* __restrict__ Wem, unsigned short* __restrict__ Wt) {
    int t = blockIdx.x * 256 + threadIdx.x;
    if (t >= L * 32 * 160) return;
    int l = t / 5120;
    int r = t % 5120;
    int n = r / 160;
    int k = r % 160;
    Wt[t] = (unsigned short)f2b(Wem[l * 5120 + k * 32 + n]);
}

// ---- Wq/Wk/Wv/Wo -> transposed bf16 hi/lo split: WT[l][mat][n][k] ----
// bf16x3 scheme: W = hi + lo with |W - hi - lo| ~ 2^-17|W|; MFMA on
// (Ah+Al)(Bh+Bl) keeping hh, hl, lh terms gives ~fp32-grade precision.
__global__ void wsplit_kernel(const float* __restrict__ Wq, const float* __restrict__ Wk,
                              const float* __restrict__ Wv, const float* __restrict__ Wo,
                              unsigned short* __restrict__ WT_hi,
                              unsigned short* __restrict__ WT_lo) {
    int t = blockIdx.x * 256 + threadIdx.x;
    if (t >= L * 4 * 64 * 64) return;
    int k = t & 63;
    int n = (t >> 6) & 63;
    int mat = (t >> 12) & 3;
    int l = t >> 14;
    const float* W = (mat == 0) ? Wq : (mat == 1) ? Wk : (mat == 2) ? Wv : Wo;
    float w = W[l * 4096 + k * 64 + n];
    unsigned short hi = (unsigned short)f2b(w);
    float lo = w - b2f(hi);
    WT_hi[t] = hi;
    WT_lo[t] = (unsigned short)f2b(lo);
}

// ---- h = node_features (fp32) + hb = bf16(node_features) ----
__global__ void hconv_kernel(const float* __restrict__ nf, float* __restrict__ h,
                             unsigned short* __restrict__ hb) {
    int t = blockIdx.x * 256 + threadIdx.x;
    if (t >= NN * D) return;
    float x = nf[t];
    h[t] = x;
    hb[t] = (unsigned short)f2b(x);
}

// ======================= per-layer kernels =======================

// ---- q = (h@Wq)*0.25 ; kv = pack(bf16(k), bf16(v)) via bf16x3 MFMA ----
// 16 nodes/block, 4 waves; wave w owns output cols w*16..w*16+15 of ALL
// three matrices (so k and v pack in-lane). No LDS.
__global__ __launch_bounds__(256, 8)
void qkv_kernel(const float* __restrict__ h,
                const unsigned short* __restrict__ WT_hi,   // this layer: [4][64][64]
                const unsigned short* __restrict__ WT_lo,
                float* __restrict__ q, unsigned int* __restrict__ kv) {
    int lane = threadIdx.x & 63;
    int wv = threadIdx.x >> 6;
    int m = lane & 15, quad = lane >> 4;
    int base = blockIdx.x * 16;

    // A-fragments: row = base+m, k-chunks {quad*8.., 32+quad*8..}, fp32 -> hi/lo
    const float* hp = h + (size_t)(base + m) * D + quad * 8;
    float af[16];
    *(f32x4*)&af[0]  = *(const f32x4*)(hp);
    *(f32x4*)&af[4]  = *(const f32x4*)(hp + 4);
    *(f32x4*)&af[8]  = *(const f32x4*)(hp + 32);
    *(f32x4*)&af[12] = *(const f32x4*)(hp + 36);
    bf16x8 a0h, a0l, a1h, a1l;
#pragma unroll
    for (int j = 0; j < 8; j++) {
        short h0 = f2b(af[j]);
        short h1 = f2b(af[8 + j]);
        a0h[j] = h0; a0l[j] = f2b(af[j] - b2f((unsigned short)h0));
        a1h[j] = h1; a1l[j] = f2b(af[8 + j] - b2f((unsigned short)h1));
    }

    f32x4 acc[3];
#pragma unroll
    for (int mat = 0; mat < 3; mat++) {
        const unsigned short* bh = WT_hi + ((size_t)mat * 64 + wv * 16 + m) * 64 + quad * 8;
        const unsigned short* bl = WT_lo + ((size_t)mat * 64 + wv * 16 + m) * 64 + quad * 8;
        bf16x8 bh0 = *(const bf16x8*)(bh);
        bf16x8 bh1 = *(const bf16x8*)(bh + 32);
        bf16x8 bl0 = *(const bf16x8*)(bl);
        bf16x8 bl1 = *(const bf16x8*)(bl + 32);
        f32x4 c = {0.f, 0.f, 0.f, 0.f};
        c = __builtin_amdgcn_mfma_f32_16x16x32_bf16(a0h, bh0, c, 0, 0, 0);
        c = __builtin_amdgcn_mfma_f32_16x16x32_bf16(a1h, bh1, c, 0, 0, 0);
        c = __builtin_amdgcn_mfma_f32_16x16x32_bf16(a0h, bl0, c, 0, 0, 0);
        c = __builtin_amdgcn_mfma_f32_16x16x32_bf16(a1h, bl1, c, 0, 0, 0);
        c = __builtin_amdgcn_mfma_f32_16x16x32_bf16(a0l, bh0, c, 0, 0, 0);
        c = __builtin_amdgcn_mfma_f32_16x16x32_bf16(a1l, bh1, c, 0, 0, 0);
        acc[mat] = c;
    }

    // C layout: col=lane&15 (-> out col wv*16+m), row=quad*4+reg (-> node)
#pragma unroll
    for (int reg = 0; reg < 4; reg++) {
        int row = base + quad * 4 + reg;
        int col = wv * 16 + m;
        q[(size_t)row * D + col] = acc[0][reg] * 0.25f;
        unsigned int kb = (unsigned short)f2b(acc[1][reg]);
        unsigned int vb = (unsigned short)f2b(acc[2][reg]);
        kv[(size_t)row * D + col] = (vb << 16) | kb;
    }
}

// ---- fused per-dst-node online-softmax attention + aggregation (8-wide) ----
__global__ void attn_kernel(const float* __restrict__ q, const unsigned int* __restrict__ kv,
                            const float* __restrict__ ebias_s,
                            const int* __restrict__ sorted_src,
                            const int* __restrict__ offsets,
                            float* __restrict__ agg) {
    int node = blockIdx.x * 4 + threadIdx.y;
    node = __builtin_amdgcn_readfirstlane(node);
    if (node >= NN) return;
    int lane = threadIdx.x;
    int hh = lane >> 4;
    float qv = q[node * D + lane];
    int beg = offsets[node];
    int end = (node == NN - 1) ? NE : offsets[node + 1];
    float mmax = -INFINITY, den = 0.f, acc = 0.f;
    int i = beg;
    for (; i + 8 <= end; i += 8) {
        int ss[8]; unsigned int kk8[8]; float bb8[8], dd[8];
#pragma unroll
        for (int u = 0; u < 8; u++) ss[u] = sorted_src[i + u];
#pragma unroll
        for (int u = 0; u < 8; u++) kk8[u] = kv[ss[u] * D + lane];
#pragma unroll
        for (int u = 0; u < 8; u++) bb8[u] = ebias_s[(i + u) * H + hh];
#pragma unroll
        for (int u = 0; u < 8; u++) dd[u] = qv * b2f_lo(kk8[u]);
#pragma unroll
        for (int off = 1; off < 16; off <<= 1) {
#pragma unroll
            for (int u = 0; u < 8; u++) dd[u] += __shfl_xor(dd[u], off, 16);
        }
        float nm = mmax;
#pragma unroll
        for (int u = 0; u < 8; u++) { dd[u] += bb8[u]; nm = fmaxf(nm, dd[u]); }
        float scale = __expf(mmax - nm);
        float ps = 0.f, av = 0.f;
#pragma unroll
        for (int u = 0; u < 8; u++) {
            float p = __expf(dd[u] - nm);
            ps += p;
            av += p * b2f_hi(kk8[u]);
        }
        den = den * scale + ps;
        acc = acc * scale + av;
        mmax = nm;
    }
    for (; i < end; i++) {
        int s = sorted_src[i];
        unsigned int kvv = kv[s * D + lane];
        float b = ebias_s[i * H + hh];
        float dot = qv * b2f_lo(kvv);
#pragma unroll
        for (int off = 1; off < 16; off <<= 1) dot += __shfl_xor(dot, off, 16);
        float score = dot + b;
        float nm = fmaxf(mmax, score);
        float scale = __expf(mmax - nm);
        float p = __expf(score - nm);
        den = den * scale + p;
        acc = acc * scale + p * b2f_hi(kvv);
        mmax = nm;
    }
    agg[node * D + lane] = acc / (den + 1e-9f);
}

// ---- h = LN(h + agg @ Wo) + bf16 shadow ; agg@Wo via bf16x3 MFMA ----
__global__ __launch_bounds__(256, 8)
void node_update_kernel(float* __restrict__ h, const float* __restrict__ agg,
                        const unsigned short* __restrict__ WoT_hi,   // [64][64]
                        const unsigned short* __restrict__ WoT_lo,
                        const float* __restrict__ gn,
                        const float* __restrict__ bn,
                        unsigned short* __restrict__ hb) {
    __shared__ float sx[16][68];
    int lane = threadIdx.x & 63;
    int wv = threadIdx.x >> 6;
    int m = lane & 15, quad = lane >> 4;
    int base = blockIdx.x * 16;

    // A-fragments from agg (fp32 -> hi/lo)
    const float* ap = agg + (size_t)(base + m) * D + quad * 8;
    float af[16];
    *(f32x4*)&af[0]  = *(const f32x4*)(ap);
    *(f32x4*)&af[4]  = *(const f32x4*)(ap + 4);
    *(f32x4*)&af[8]  = *(const f32x4*)(ap + 32);
    *(f32x4*)&af[12] = *(const f32x4*)(ap + 36);
    bf16x8 a0h, a0l, a1h, a1l;
#pragma unroll
    for (int j = 0; j < 8; j++) {
        short h0 = f2b(af[j]);
        short h1 = f2b(af[8 + j]);
        a0h[j] = h0; a0l[j] = f2b(af[j] - b2f((unsigned short)h0));
        a1h[j] = h1; a1l[j] = f2b(af[8 + j] - b2f((unsigned short)h1));
    }
    const unsigned short* bh = WoT_hi + ((size_t)wv * 16 + m) * 64 + quad * 8;
    const unsigned short* bl = WoT_lo + ((size_t)wv * 16 + m) * 64 + quad * 8;
    bf16x8 bh0 = *(const bf16x8*)(bh);
    bf16x8 bh1 = *(const bf16x8*)(bh + 32);
    bf16x8 bl0 = *(const bf16x8*)(bl);
    bf16x8 bl1 = *(const bf16x8*)(bl + 32);
    f32x4 c = {0.f, 0.f, 0.f, 0.f};
    c = __builtin_amdgcn_mfma_f32_16x16x32_bf16(a0h, bh0, c, 0, 0, 0);
    c = __builtin_amdgcn_mfma_f32_16x16x32_bf16(a1h, bh1, c, 0, 0, 0);
    c = __builtin_amdgcn_mfma_f32_16x16x32_bf16(a0h, bl0, c, 0, 0, 0);
    c = __builtin_amdgcn_mfma_f32_16x16x32_bf16(a1h, bl1, c, 0, 0, 0);
    c = __builtin_amdgcn_mfma_f32_16x16x32_bf16(a0l, bh0, c, 0, 0, 0);
    c = __builtin_amdgcn_mfma_f32_16x16x32_bf16(a1l, bh1, c, 0, 0, 0);

    // x = h + dot -> LDS (C layout: col=wv*16+m, row=quad*4+reg)
#pragma unroll
    for (int reg = 0; reg < 4; reg++) {
        int row = quad * 4 + reg;
        int col = wv * 16 + m;
        sx[row][col] = c[reg] + h[(size_t)(base + row) * D + col];
    }
    __syncthreads();

    float gcol = gn[lane], bcol = bn[lane];
#pragma unroll
    for (int it = 0; it < 4; it++) {
        int ln = wv * 4 + it;
        int node = base + ln;
        float x = sx[ln][lane];
        float sum = x, sq = x * x;
#pragma unroll
        for (int off = 32; off; off >>= 1) {
            sum += __shfl_xor(sum, off);
            sq += __shfl_xor(sq, off);
        }
        float mu = sum * (1.f / 64.f);
        float var = sq * (1.f / 64.f) - mu * mu;
        float out = (x - mu) * rsqrtf(var + 1e-5f) * gcol + bcol;
        h[(size_t)node * D + lane] = out;
        hb[(size_t)node * D + lane] = (unsigned short)f2b(out);
    }
}

// ---- e = LN(e + gelu([h[src]|h[dst]|e] @ Wem + bem)) via bf16 MFMA. ----
__global__ __launch_bounds__(256, 4)
void edge_update_mfma_kernel(const unsigned short* __restrict__ hb,
                             unsigned short* __restrict__ eb_s,
                             const int* __restrict__ sorted_src,
                             const int* __restrict__ sorted_dst,
                             const unsigned short* __restrict__ Wt,   // [32][160] bf16
                             const float* __restrict__ bem,
                             const float* __restrict__ ge,
                             const float* __restrict__ be,
                             const float* __restrict__ We_next,       // [32][4]
                             float* __restrict__ ebias_s,
                             int do_bias, int do_estore) {
    __shared__ __align__(16) unsigned short sWt[32][168];  // 160 + 8 pad
    __shared__ __align__(16) float ytr[4][16][36];
    int tid = threadIdx.x;
    int wave = tid >> 6;
    int lane = tid & 63;
    int we = blockIdx.x * 64 + wave * 16;       // first sorted position of this wave
    int m = lane & 15;
    int quad = lane >> 4;
    int p_m = we + m;
    int s_idx = sorted_src[p_m], d_idx = sorted_dst[p_m];

    // issue all gathers up-front (latency overlaps the weight staging below)
    const unsigned short* as = hb + (size_t)s_idx * D + quad * 8;
    const unsigned short* ad = hb + (size_t)d_idx * D + quad * 8;
    bf16x8 a_s0 = *(const bf16x8*)(as);
    bf16x8 a_s1 = *(const bf16x8*)(as + 32);
    bf16x8 a_d0 = *(const bf16x8*)(ad);
    bf16x8 a_d1 = *(const bf16x8*)(ad + 32);
    bf16x8 ea = *(const bf16x8*)(eb_s + (size_t)p_m * DE + quad * 8);

    // stage Wt[32][160] -> sWt[32][168] (2560 dwords, 10 per thread)
    {
        const unsigned int* Wt32 = (const unsigned int*)Wt;
#pragma unroll
        for (int it = 0; it < 10; it++) {
            int i = tid + it * 256;
            int sh = i * 2;
            int r = sh / 160, c = sh % 160;
            *(unsigned int*)&sWt[r][c] = Wt32[i];
        }
    }

    // B-fragment of We_next (bias MFMA): lane holds
    // B[k=quad*8+j][n=m] = We_next[(quad*8+j)*4 + m] for m<4, else 0.
    bf16x8 wb;
#pragma unroll
    for (int j = 0; j < 8; j++) {
        float w = (do_bias && m < 4) ? We_next[(quad * 8 + j) * 4 + m] : 0.f;
        wb[j] = f2b(w);
    }

    __syncthreads();    // weights staged

    f32x4 c0 = {0.f, 0.f, 0.f, 0.f};
    f32x4 c1 = {0.f, 0.f, 0.f, 0.f};
    const unsigned short* w0 = &sWt[m][quad * 8];
    const unsigned short* w1 = &sWt[m + 16][quad * 8];

#pragma unroll
    for (int ks = 0; ks < 4; ks++) {
        bf16x8 a = (ks == 0) ? a_s0 : (ks == 1) ? a_s1 : (ks == 2) ? a_d0 : a_d1;
        bf16x8 b0 = *(const bf16x8*)(w0 + ks * 32);
        bf16x8 b1 = *(const bf16x8*)(w1 + ks * 32);
        c0 = __builtin_amdgcn_mfma_f32_16x16x32_bf16(a, b0, c0, 0, 0, 0);
        c1 = __builtin_amdgcn_mfma_f32_16x16x32_bf16(a, b1, c1, 0, 0, 0);
    }
    {
        bf16x8 b0 = *(const bf16x8*)(w0 + 4 * 32);
        bf16x8 b1 = *(const bf16x8*)(w1 + 4 * 32);
        c0 = __builtin_amdgcn_mfma_f32_16x16x32_bf16(ea, b0, c0, 0, 0, 0);
        c1 = __builtin_amdgcn_mfma_f32_16x16x32_bf16(ea, b1, c1, 0, 0, 0);
    }

    // gelu(mfma + bem) in C-layout (col=m / m+16, row=quad*4+reg) -> LDS
    float bm0 = bem[m], bm1 = bem[m + 16];
#pragma unroll
    for (int reg = 0; reg < 4; reg++) {
        int row = quad * 4 + reg;
        float y0 = c0[reg] + bm0;
        float y1 = c1[reg] + bm1;
        float u0 = 1.5957691216057308f * (y0 + 0.044715f * y0 * y0 * y0);
        float u1 = 1.5957691216057308f * (y1 + 0.044715f * y1 * y1 * y1);
        float t0 = 1.f - 2.f / (1.f + __expf(u0));
        float t1 = 1.f - 2.f / (1.f + __expf(u1));
        ytr[wave][row][m] = 0.5f * y0 * (1.f + t0);
        ytr[wave][row][m + 16] = 0.5f * y1 * (1.f + t1);
    }
    __syncthreads();

    // row-owned: lane handles edge (we+m), cols quad*8..+8
    float y[8];
    *(f32x4*)&y[0] = *(const f32x4*)&ytr[wave][m][quad * 8];
    *(f32x4*)&y[4] = *(const f32x4*)&ytr[wave][m][quad * 8 + 4];
    float s = 0.f, sq = 0.f;
#pragma unroll
    for (int j = 0; j < 8; j++) {
        y[j] += b2f((unsigned short)ea[j]);      // residual (free, from A-frag)
        s += y[j];
        sq += y[j] * y[j];
    }
    s += __shfl_xor(s, 16); s += __shfl_xor(s, 32);
    sq += __shfl_xor(sq, 16); sq += __shfl_xor(sq, 32);
    float mu = s * (1.f / 32.f);
    float var = sq * (1.f / 32.f) - mu * mu;
    float inv = rsqrtf(var + 1e-5f);

    float4 g0 = *(const float4*)(ge + quad * 8);
    float4 g1 = *(const float4*)(ge + quad * 8 + 4);
    float4 b0 = *(const float4*)(be + quad * 8);
    float4 b1 = *(const float4*)(be + quad * 8 + 4);
    float gg[8] = {g0.x, g0.y, g0.z, g0.w, g1.x, g1.y, g1.z, g1.w};
    float bbv[8] = {b0.x, b0.y, b0.z, b0.w, b1.x, b1.y, b1.z, b1.w};
    bf16x8 zb;
#pragma unroll
    for (int j = 0; j < 8; j++) {
        float z = (y[j] - mu) * inv * gg[j] + bbv[j];
        zb[j] = f2b(z);
    }
    if (do_estore) {
        *(s16x8*)(eb_s + (size_t)p_m * DE + quad * 8) = zb;
    }
    if (do_bias) {
        // bias[edge][head] = z · We_next : z is directly an A-fragment
        f32x4 db = {0.f, 0.f, 0.f, 0.f};
        db = __builtin_amdgcn_mfma_f32_16x16x32_bf16(zb, wb, db, 0, 0, 0);
        // D layout: col=lane&15 = head, row=quad*4+reg = edge-in-group
        if (m < 4) {
#pragma unroll
            for (int reg = 0; reg < 4; reg++) {
                ebias_s[(we + quad * 4 + reg) * H + m] = db[reg];
            }
        }
    }
}

extern "C" void kernel_launch(void* const* d_in, const int* in_sizes, int n_in,
                              void* d_out, int out_size, void* d_ws, size_t ws_size,
                              hipStream_t stream) {
    const float* node_features = (const float*)d_in[0];
    const float* e = (const float*)d_in[1];   // pristine fp32 e (read-only)
    const int* edge_index = (const int*)d_in[2];
    const int* src = edge_index;
    const int* dst = edge_index + NE;
    const float* Wq = (const float*)d_in[3];
    const float* Wk = (const float*)d_in[4];
    const float* Wv = (const float*)d_in[5];
    const float* Wo = (const float*)d_in[6];
    const float* We = (const float*)d_in[7];
    const float* Wem = (const float*)d_in[8];
    const float* bem = (const float*)d_in[9];
    const float* gn = (const float*)d_in[10];
    const float* bn = (const float*)d_in[11];
    const float* ge = (const float*)d_in[12];
    const float* be = (const float*)d_in[13];

    float* h = (float*)d_out;       // h lives in d_out

    float* ws = (float*)d_ws;
    float* q = ws;                                       // N*D f32
    unsigned int* kv = (unsigned int*)(q + NN * D);      // N*D u32 (packed bf16 k|v)
    float* agg = (float*)(kv + NN * D);                  // N*D f32
    float* ebias_s = agg + NN * D;                       // E*H f32 (sorted order)
    int* offsets = (int*)(ebias_s + (size_t)NE * H);     // NN
    int* cursor = offsets + NN;                          // NN
    int* bsum = cursor + NN;                             // 64
    int* sorted_eid = bsum + 64;                         // NE
    int* sorted_src = sorted_eid + NE;                   // NE
    int* sorted_dst = sorted_src + NE;                   // NE
    unsigned short* Wt = (unsigned short*)(sorted_dst + NE);  // L*32*160 bf16
    unsigned short* hb = Wt + L * 32 * 160;              // N*D bf16
    unsigned short* eb_s = hb + NN * D;                  // E*DE bf16 e-state (sorted)
    unsigned short* WT_hi = eb_s + (size_t)NE * DE;      // L*4*64*64 bf16
    unsigned short* WT_lo = WT_hi + L * 4 * 64 * 64;     // L*4*64*64 bf16

    const int NB = (NN + 1023) / 1024;

    // ---- CSR build + preconverts (inputs constant; rebuilt every launch) ----
    hipMemsetAsync(cursor, 0, NN * sizeof(int), stream);
    deg_kernel<<<(NE + 255) / 256, 256, 0, stream>>>(dst, cursor);
    block_sum_kernel<<<NB, 256, 0, stream>>>(cursor, bsum);
    scan_bsum_kernel<<<1, 64, 0, stream>>>(bsum, NB);
    scan_block_kernel<<<NB, 256, 0, stream>>>(cursor, bsum, offsets);
    hipMemsetAsync(cursor, 0, NN * sizeof(int), stream);
    scatter_kernel<<<(NE + 255) / 256, 256, 0, stream>>>(src, dst, offsets, cursor,
                                                         sorted_eid, sorted_src, sorted_dst);
    // eperm also produces the layer-0 edge bias (fused, from pristine fp32 e)
    eperm_kernel<<<(NE * 4 + 255) / 256, 256, 0, stream>>>(e, sorted_eid, We, eb_s, ebias_s);
    wconv_kernel<<<(L * 32 * 160 + 255) / 256, 256, 0, stream>>>(Wem, Wt);
    wsplit_kernel<<<(L * 4 * 64 * 64 + 255) / 256, 256, 0, stream>>>(Wq, Wk, Wv, Wo,
                                                                     WT_hi, WT_lo);
    hconv_kernel<<<(NN * D + 255) / 256, 256, 0, stream>>>(node_features, h, hb);

    for (int layer = 0; layer < L; layer++) {
        const unsigned short* WT_hi_l = WT_hi + (size_t)layer * 4 * 4096;
        const unsigned short* WT_lo_l = WT_lo + (size_t)layer * 4 * 4096;
        const unsigned short* Wt_l = Wt + layer * 32 * 160;
        const float* bem_l = bem + layer * DE;
        const float* gn_l = gn + layer * D;
        const float* bn_l = bn + layer * D;
        const float* ge_l = ge + layer * DE;
        const float* be_l = be + layer * DE;

        qkv_kernel<<<NN / 16, 256, 0, stream>>>(h, WT_hi_l, WT_lo_l, q, kv);
        attn_kernel<<<NN / 4, dim3(64, 4), 0, stream>>>(q, kv, ebias_s, sorted_src,
                                                        offsets, agg);
        node_update_kernel<<<NN / 16, 256, 0, stream>>>(h, agg,
                                                        WT_hi_l + 3 * 4096,
                                                        WT_lo_l + 3 * 4096,
                                                        gn_l, bn_l, hb);
        // layer 0: full edge update; layer 1: bias-only; layer 2: skipped
        if (layer < L - 1) {
            const float* We_next = We + (layer + 1) * DE * H;
            edge_update_mfma_kernel<<<NE / 64, 256, 0, stream>>>(hb, eb_s, sorted_src,
                                                                 sorted_dst, Wt_l,
                                                                 bem_l, ge_l, be_l,
                                                                 We_next, ebias_s,
                                                                 1, layer == 0 ? 1 : 0);
        }
    }
}